// Round 9
// baseline (298.526 us; speedup 1.0000x reference)
//
#include <hip/hip_runtime.h>
#include <stdint.h>

#define Bb 64
#define Hh 128
#define Ww 128
#define Cc 21
#define Pp 49152          // NUM_SAMPLED
#define Kk 36864          // NUM_UNCERTAIN
#define NR 12288          // NUM_RANDOM

// Digit split 10/10/11 over key bits [16,47): passes 0,1 use 10-bit digits
// (write runs ~4); pass 2 gets the 11-bit exponent-dominated digit (skewed
// -> long runs -> coalesced writes).
#define NB0 1024          // pass 0/1 bins
#define NB2 2048          // pass 2 bins
#define TILE 4096         // elements per sort tile
#define TILES 12          // Pp / TILE
#define NBLK (Bb * TILES) // 768 blocks
#define NTHR 512          // 8 waves/block (R8: same LDS/tile, 2x waves/CU)

typedef uint32_t u32;
typedef uint64_t u64;
typedef unsigned short u16;

// XCD-affine decode: all TILES blocks of segment s have blk%8 == s%8 ->
// segment's r/w window (keys, hist, slab) stays in one XCD's L2. Heuristic.
#define DECODE_ST const int s = blk & 63; const int t = blk >> 6;

// N-bit ballot digit-match: mask of lanes in this wave holding digit d.
template<int NBITS>
__device__ __forceinline__ u64 matchN(u32 d) {
    u64 m = ~0ull;
    #pragma unroll
    for (int bit = 0; bit < NBITS; ++bit) {
        u64 bl = __ballot((d >> bit) & 1u);
        m &= ((d >> bit) & 1u) ? bl : ~bl;
    }
    return m;
}

// ---------------------------------------------------------------------------
// Kernel 0: vectorized ch-0 extract. Dense float4 reads (R4 lesson: 84B-
// strided scalar reads are latency-bound at 1.8 TB/s; dense float4 ~6 TB/s).
// ---------------------------------------------------------------------------
__global__ __launch_bounds__(256) void extract_kernel(const float* __restrict__ lg,
                                                      float* __restrict__ planes) {
    const u32 gtid = blockIdx.x * 256 + threadIdx.x;   // [0, 262144)
    const float4* l4 = (const float4*)lg;
    #pragma unroll
    for (u32 it = 0; it < 21; ++it) {
        u32 g = it * 262144u + gtid;                   // [0, 5505024)
        float4 v = l4[g];
        u32 base = g * 4u;
        u32 k = (base + 20u) / 21u;                    // first px with ch0 >= base
        u32 pos = k * 21u - base;
        if (pos < 4u) {
            float val = (pos == 0u) ? v.x : (pos == 1u) ? v.y : (pos == 2u) ? v.z : v.w;
            planes[k] = val;
        }
    }
}

// ---------------------------------------------------------------------------
// Kernel 1: bilinear sample (64 KB compact plane staged via float4), key
// build, fused pass-0 (10-bit) hist. key = fp32 bits of |interp| (order-
// isomorphic, non-negative); element = (key<<16)|idx; LSD stability supplies
// the idx tie-break (jax.lax.top_k). fp contract OFF: bit-exact required.
// ---------------------------------------------------------------------------
__global__ __launch_bounds__(512, 4) void sample_key_kernel(const float* __restrict__ planes,
                                                            const float2* __restrict__ coords,
                                                            u64* __restrict__ keys,
                                                            u32* __restrict__ hist) {
#pragma clang fp contract(off)
    __shared__ float pl[Hh * Ww];      // 64 KB
    __shared__ u32 h[NB0];             // 4 KB
    const int tid = threadIdx.x;
    const int blk = blockIdx.x;
    DECODE_ST

    for (int i = tid; i < NB0; i += NTHR) h[i] = 0;
    const float4* p4 = (const float4*)(planes + (size_t)s * (Hh * Ww));
    float4* l4 = (float4*)pl;
    #pragma unroll
    for (int i = 0; i < 8; ++i) l4[i * NTHR + tid] = p4[i * NTHR + tid];
    __syncthreads();

    #pragma unroll 4
    for (int i = 0; i < 8; ++i) {
        int idx = t * TILE + i * NTHR + tid;           // point index within segment
        int gid = s * Pp + idx;
        float2 c = coords[gid];
        float xf = c.x * 127.0f;                       // coords[...,0] -> H axis
        float yf = c.y * 127.0f;                       // coords[...,1] -> W axis
        float x0 = floorf(xf), x1 = ceilf(xf);
        float y0 = floorf(yf), y1 = ceilf(yf);
        float mux = xf - x0;
        float muy = yf - y0;
        int x0i = (int)x0, x1i = (int)x1, y0i = (int)y0, y1i = (int)y1;
        float p1  = pl[x0i * Ww + y0i];
        float p2  = pl[x1i * Ww + y0i];
        float p3  = pl[x0i * Ww + y1i];
        float p4v = pl[x1i * Ww + y1i];
        float p12 = p1 * (1.0f - mux) + p2 * mux;
        float p34 = p3 * (1.0f - mux) + p4v * mux;
        float r   = p12 * (1.0f - muy) + p34 * muy;
        u32 kb = __float_as_uint(r) & 0x7fffffffu;     // |r| bits
        keys[gid] = ((u64)kb << 16) | (u32)idx;
        atomicAdd(&h[kb & (NB0 - 1)], 1u);             // pass-0 digit (uniform)
    }
    __syncthreads();
    const size_t hbase = ((size_t)s * TILES + t) * NB0;
    for (int d = tid; d < NB0; d += NTHR) hist[hbase + d] = h[d];
}

// ---------------------------------------------------------------------------
// hist32 (pass 2 only): per-wave privatized tables. Pass-2 digit is SKEWED;
// 4 tables / 256 thr keeps hot-bin atomic serialization bounded.
// ---------------------------------------------------------------------------
__global__ __launch_bounds__(256) void hist32_kernel(const u32* __restrict__ in,
                                                     u32* __restrict__ hist) {
    __shared__ u32 h[4][NB2];          // 32 KB
    const int tid = threadIdx.x;
    const int w = tid >> 6;
    const int blk = blockIdx.x;
    DECODE_ST
    for (int i = tid; i < 4 * NB2; i += 256) ((u32*)h)[i] = 0;
    __syncthreads();
    const u32* src = in + (size_t)s * Pp + t * TILE;
    #pragma unroll 4
    for (int i = 0; i < 16; ++i) {
        u32 v = src[i * 256 + tid];
        atomicAdd(&h[w][(v >> 16) & (NB2 - 1)], 1u);   // 11-bit top digit
    }
    __syncthreads();
    const size_t hbase = ((size_t)s * TILES + t) * NB2;
    #pragma unroll
    for (int j = 0; j < NB2 / 256; ++j) {
        int d = j * 256 + tid;
        hist[hbase + d] = h[0][d] + h[1][d] + h[2][d] + h[3][d];
    }
}

// ---------------------------------------------------------------------------
// Offset derivation: seg tables (segtot[d], pre[d] = sum over tiles < t),
// staged in scan scratch (head of el, dead until phase B); dual block-scan
// packed in u64 (local count low word, segment count high; no cross-carry).
// ---------------------------------------------------------------------------
template<int NB>
__device__ __forceinline__ void fill_seg_tables(u32* sc1v, u32* sc2v,
                                                const u32* hb, int t, int tid) {
    for (int d = tid; d < NB; d += NTHR) {
        u32 tot = 0, pre = 0;
        #pragma unroll
        for (int tt = 0; tt < TILES; ++tt) {
            u32 cv = hb[tt * NB + d];       // coalesced, L2-hot
            tot += cv;
            pre += (tt < t) ? cv : 0;
        }
        sc1v[d] = tot;
        sc2v[d] = pre;
    }
}

// Slab variant (pass 1): hist1[s][t2][d] = sum_{ts} slab[s][ts][t2][d].
__device__ __forceinline__ void fill_seg_tables_slab(u32* sc1v, u32* sc2v,
                                                     const u16* slabseg, int t, int tid) {
    for (int d = tid; d < NB0; d += NTHR) {
        u32 tot = 0, pre = 0;
        #pragma unroll
        for (int t2 = 0; t2 < TILES; ++t2) {
            u32 c = 0;
            #pragma unroll
            for (int ts = 0; ts < TILES; ++ts)
                c += slabseg[ts * (TILES * NB0) + t2 * NB0 + d];   // coalesced u16
            tot += c;
            pre += (t2 < t) ? c : 0;
        }
        sc1v[d] = tot;
        sc2v[d] = pre;
    }
}

// wh layout: [digit][8 waves] u16.
template<int NB>
__device__ __forceinline__ void block_scan(const u32* sc1v, const u32* sc2v,
                                           u16* wh, u16* dl, u64* aux,
                                           int tid, int lane, int w) {
    constexpr int DPB = NB / NTHR;          // digits per thread (2 or 4)
    const int d0 = tid * DPB;
    u32 dtot[DPB], gtot[DPB], gpre[DPB];
    u32 t8l = 0, t8g = 0;
    #pragma unroll
    for (int j = 0; j < DPB; ++j) {
        int d = d0 + j;
        u32 cv = 0;
        #pragma unroll
        for (int k = 0; k < 8; ++k) cv += wh[d * 8 + k];
        dtot[j] = cv; t8l += cv;
        gtot[j] = sc1v[d]; gpre[j] = sc2v[d]; t8g += gtot[j];
    }
    u64 own = ((u64)t8g << 32) | t8l;
    u64 sc = own;
    for (int o = 1; o < 64; o <<= 1) {
        u64 n = __shfl_up((unsigned long long)sc, o);
        if (lane >= o) sc += n;
    }
    if (lane == 63) aux[w] = sc;
    __syncthreads();
    if (tid == 0) {
        u64 run = 0;
        #pragma unroll
        for (int i = 0; i < 8; ++i) { u64 x = aux[i]; aux[i] = run; run += x; }
    }
    __syncthreads();
    u64 excl = sc - own + aux[w];
    u32 run_l = (u32)excl;                  // local exclusive base
    u32 run_g = (u32)(excl >> 32);          // segment digit-exclusive base
    #pragma unroll
    for (int j = 0; j < DPB; ++j) {
        int d = d0 + j;
        u32 ls = run_l;
        u32 g = run_g + gpre[j];            // off[s][d][t]
        dl[d] = (u16)(g - ls);              // exact mod 2^16 (Pp < 65536)
        u32 acc = ls;
        #pragma unroll
        for (int k = 0; k < 8; ++k) {
            u32 ck = wh[d * 8 + k];
            wh[d * 8 + k] = (u16)acc;
            acc += ck;
        }
        run_l += dtot[j];
        run_g += gtot[j];
    }
}

// ---------------------------------------------------------------------------
// Scatter (u64 passes 0,1): stable LDS reorder + run-contiguous global write.
// MAKE_SLAB (pass 0): phase D — after phase C, el+wh (48 KB) are dead; a u32
// tab[12][1024] overlays them; each element's (dest-tile t2, next-digit d1),
// captured in phase C (reusing dg[]), is LDS-atomically counted, then the
// block writes its u16 slab slice [t2][d1]. This replaces the hist64 kernel
// (kills a dispatch + a 25 MB re-read).
// USE_SLAB (pass 1): prologue sums the 12 source-tile slab slices (L2-hot).
// COMPRESS (pass 1): emit u32 (key[36,47)<<16)|idx — bits [16,36) spent.
// ---------------------------------------------------------------------------
template<int SHIFT, bool COMPRESS, bool MAKE_SLAB, bool USE_SLAB>
__global__ __launch_bounds__(512, 6) void scatter64_kernel(const u64* __restrict__ in,
                                                           void* __restrict__ outbuf,
                                                           const u32* __restrict__ hist,
                                                           u16* __restrict__ slab) {
    __shared__ union {
        struct { u64 el[TILE]; u16 wh[NB0 * 8]; } a;   // 48 KB (live thru phase C)
        u32 tab[TILES * NB0];                          // 48 KB (phase D overlay)
    } smu;
    __shared__ u16 dl[NB0];            // 2 KB (live thru phase C; NOT overlaid)
    __shared__ u64 aux[8];
    u64* el = smu.a.el;
    u16* wh = smu.a.wh;
    const int tid = threadIdx.x;
    const int lane = tid & 63;
    const int w = tid >> 6;
    const int blk = blockIdx.x;
    DECODE_ST
    const u64* src = in + (size_t)s * Pp + t * TILE;

    for (int i = tid; i < NB0 * 4; i += NTHR) ((u32*)wh)[i] = 0;
    u64 v[8];
    #pragma unroll
    for (int i = 0; i < 8; ++i) v[i] = src[w * 512 + i * 64 + lane];
    if constexpr (USE_SLAB) {
        fill_seg_tables_slab((u32*)el, (u32*)el + NB0,
                             slab + (size_t)s * (TILES * TILES * NB0), t, tid);
    } else {
        fill_seg_tables<NB0>((u32*)el, (u32*)el + NB0,
                             hist + (size_t)s * (TILES * NB0), t, tid);
    }
    __syncthreads();

    const u64 ltmask = (1ull << lane) - 1ull;
    u32 dg[8], pk[8];
    volatile u16* vwh = wh;
    #pragma unroll 2
    for (int i = 0; i < 8; ++i) {
        u32 d = (u32)(v[i] >> SHIFT) & (NB0 - 1);
        u64 m = matchN<10>(d);
        u32 before = (u32)__popcll(m & ltmask);
        u32 cnt = (u32)__popcll(m);
        bool lead = (lane == __ffsll((unsigned long long)m) - 1);
        dg[i] = d;
        pk[i] = before | (cnt << 8) | (lead ? 0x10000u : 0u);
        if (lead) { u32 p = d * 8 + w; vwh[p] = (u16)(vwh[p] + cnt); }
    }
    __syncthreads();
    block_scan<NB0>((const u32*)el, (const u32*)el + NB0, wh, dl, aux, tid, lane, w);
    __syncthreads();

    for (int i = 0; i < 8; ++i) {
        u32 d = dg[i];
        u32 before = pk[i] & 0xffu;
        u32 base = vwh[d * 8 + w];
        el[base + before] = v[i];
        if (pk[i] & 0x10000u) vwh[d * 8 + w] = (u16)(base + ((pk[i] >> 8) & 0xffu));
    }
    __syncthreads();

    // phase C: linear read-back, run-contiguous write; capture (t2,d1) in dg[]
    if constexpr (!COMPRESS) {
        u64* dst = (u64*)outbuf + (size_t)s * Pp;
        for (int i = 0; i < 8; ++i) {
            int pos = i * NTHR + tid;
            u64 e = el[pos];
            u32 d = (u32)(e >> SHIFT) & (NB0 - 1);
            u32 g = (u32)(u16)(pos + dl[d]);
            dst[g] = e;
            if constexpr (MAKE_SLAB)
                dg[i] = (g >> 12) * NB0 + ((u32)(e >> 26) & (NB0 - 1));
        }
    } else {
        u32* dst = (u32*)outbuf + (size_t)s * Pp;
        for (int i = 0; i < 8; ++i) {
            int pos = i * NTHR + tid;
            u64 e = el[pos];
            u32 d = (u32)(e >> SHIFT) & (NB0 - 1);
            u32 g = (u32)(u16)(pos + dl[d]);
            dst[g] = ((u32)(e >> 36) << 16) | (u32)(e & 0xffffu);   // key[36,47) | idx
            if constexpr (MAKE_SLAB)
                dg[i] = (g >> 12) * NB0 + ((u32)(e >> 26) & (NB0 - 1));
        }
    }

    if constexpr (MAKE_SLAB) {
        __syncthreads();                       // el/wh dead -> tab overlay safe
        for (int i = tid; i < TILES * NB0; i += NTHR) smu.tab[i] = 0;
        __syncthreads();
        #pragma unroll
        for (int i = 0; i < 8; ++i) atomicAdd(&smu.tab[dg[i]], 1u);
        __syncthreads();
        u16* sl = slab + ((size_t)s * TILES + t) * (TILES * NB0);
        for (int i = tid; i < TILES * NB0; i += NTHR) sl[i] = (u16)smu.tab[i];
    }
}

// ---------------------------------------------------------------------------
// Final scatter (u32, 11-bit top digit): rank -> g; emit out[s][g] =
// coords[s][idx] for g < K; fused extra_random copy into rows [K, P).
// LDS: 16K el32 + 32K wh + 4K dl = 53.3 KB -> 3 blocks/CU (159.9 <= 160).
// ---------------------------------------------------------------------------
__global__ __launch_bounds__(512, 6) void scatter32_final_kernel(const u32* __restrict__ in,
                                                                 const u32* __restrict__ hist,
                                                                 const float2* __restrict__ coords,
                                                                 const float2* __restrict__ extra,
                                                                 float2* __restrict__ out) {
    __shared__ u32 el32[TILE];         // 16 KB (head = scan scratch pre-B)
    __shared__ u16 wh[NB2 * 8];        // 32 KB
    __shared__ u16 dl[NB2];            // 4 KB
    __shared__ u64 aux[8];
    const int tid = threadIdx.x;
    const int lane = tid & 63;
    const int w = tid >> 6;
    const int blk = blockIdx.x;
    DECODE_ST
    const u32* src = in + (size_t)s * Pp + t * TILE;

    for (int i = tid; i < NB2 * 4; i += NTHR) ((u32*)wh)[i] = 0;
    u32 v[8];
    #pragma unroll
    for (int i = 0; i < 8; ++i) v[i] = src[w * 512 + i * 64 + lane];
    fill_seg_tables<NB2>((u32*)el32, (u32*)el32 + NB2, hist + (size_t)s * (TILES * NB2), t, tid);
    __syncthreads();

    const u64 ltmask = (1ull << lane) - 1ull;
    u32 dg[8], pk[8];
    volatile u16* vwh = wh;
    #pragma unroll 2
    for (int i = 0; i < 8; ++i) {
        u32 d = (v[i] >> 16) & (NB2 - 1);
        u64 m = matchN<11>(d);
        u32 before = (u32)__popcll(m & ltmask);
        u32 cnt = (u32)__popcll(m);
        bool lead = (lane == __ffsll((unsigned long long)m) - 1);
        dg[i] = d;
        pk[i] = before | (cnt << 8) | (lead ? 0x10000u : 0u);
        if (lead) { u32 p = d * 8 + w; vwh[p] = (u16)(vwh[p] + cnt); }
    }
    __syncthreads();
    block_scan<NB2>((const u32*)el32, (const u32*)el32 + NB2, wh, dl, aux, tid, lane, w);
    __syncthreads();

    for (int i = 0; i < 8; ++i) {
        u32 d = dg[i];
        u32 before = pk[i] & 0xffu;
        u32 base = vwh[d * 8 + w];
        el32[base + before] = v[i];
        if (pk[i] & 0x10000u) vwh[d * 8 + w] = (u16)(base + ((pk[i] >> 8) & 0xffu));
    }
    __syncthreads();

    const float2* cseg = coords + (size_t)s * Pp;
    float2* oseg = out + (size_t)s * Pp;
    for (int i = 0; i < 8; ++i) {
        int pos = i * NTHR + tid;
        u32 e = el32[pos];
        u32 d = (e >> 16) & (NB2 - 1);
        u32 g = (u32)(u16)(pos + dl[d]);
        if (g < Kk) oseg[g] = cseg[e & 0xffffu];
    }
    const float2* eseg = extra + (size_t)s * NR;
    float2* xseg = out + (size_t)s * Pp + Kk;
    #pragma unroll
    for (int i = 0; i < 2; ++i) {
        int p = t * 1024 + i * NTHR + tid;
        xseg[p] = eseg[p];
    }
}

extern "C" void kernel_launch(void* const* d_in, const int* in_sizes, int n_in,
                              void* d_out, int out_size, void* d_ws, size_t ws_size,
                              hipStream_t stream) {
    (void)in_sizes; (void)n_in; (void)out_size; (void)ws_size;
    const float*  logits = (const float*)d_in[0];   // (B,H,W,C) fp32
    const float2* coords = (const float2*)d_in[1];  // (B,P,2)  fp32
    const float2* extra  = (const float2*)d_in[2];  // (B,NR,2) fp32
    float2* out = (float2*)d_out;

    u64* buf0 = (u64*)d_ws;                          // 25.2 MB
    u64* buf1 = buf0 + (size_t)Bb * Pp;              // 25.2 MB (ping-pong)
    float* planes = (float*)buf1;                    // 4 MB; dead before pass-0 scatter writes buf1
    u32* histA = (u32*)d_out;                        // 3.1 MB pass-0 hist (d_out scratch)
    u16* slab  = (u16*)((char*)d_out + (4 << 20));   // 18.9 MB pass-1 slab (d_out+4MB..22.9MB)
    u32* histB = (u32*)buf1;                         // pass-2 hist (6.3 MB); buf1 dead after pass-1 scatter

    // ch-0 extract (dense float4) -> compact planes
    extract_kernel<<<1024, 256, 0, stream>>>(logits, planes);
    // sample: planes,coords -> keys(buf0,u64) + pass-0 hist (10-bit)
    sample_key_kernel<<<NBLK, NTHR, 0, stream>>>(planes, coords, buf0, histA);
    // pass 0: bits [16,26)  buf0 -> buf1; phase D emits pass-1 slab
    scatter64_kernel<16, false, true, false><<<NBLK, NTHR, 0, stream>>>(buf0, buf1, histA, slab);
    // pass 1: bits [26,36)  buf1 -> buf0(u32: key[36,47)|idx); offsets from slab
    scatter64_kernel<26, true, false, true><<<NBLK, NTHR, 0, stream>>>(buf1, buf0, nullptr, slab);
    // pass 2: 11-bit top digit  buf0(u32) -> out (fused gather+emit+extra)
    hist32_kernel<<<NBLK, 256, 0, stream>>>((const u32*)buf0, histB);
    scatter32_final_kernel<<<NBLK, NTHR, 0, stream>>>((const u32*)buf0, histB, coords, extra, out);
}

// Round 10
// 285.077 us; speedup vs baseline: 1.0472x; 1.0472x over previous
//
#include <hip/hip_runtime.h>
#include <stdint.h>

#define Bb 64
#define Hh 128
#define Ww 128
#define Cc 21
#define Pp 49152          // NUM_SAMPLED
#define Kk 36864          // NUM_UNCERTAIN
#define NR 12288          // NUM_RANDOM

// Digit split 10/10/11 over key bits [16,47): passes 0,1 use 10-bit digits
// (write runs ~4); pass 2 gets the 11-bit exponent-dominated digit (skewed
// -> long runs -> coalesced writes).
#define NB0 1024          // pass 0/1 bins
#define NB2 2048          // pass 2 bins
#define TILE 4096         // elements per sort tile
#define TILES 12          // Pp / TILE
#define NBLK (Bb * TILES) // 768 blocks
#define NTHR 512          // 8 waves/block (R8: same LDS/tile, 2x waves/CU)

typedef uint32_t u32;
typedef uint64_t u64;
typedef unsigned short u16;

// XCD-affine decode: all TILES blocks of segment s have blk%8 == s%8 ->
// segment's r/w window stays in one XCD's L2. Heuristic only.
#define DECODE_ST const int s = blk & 63; const int t = blk >> 6;

// N-bit ballot digit-match: mask of lanes in this wave holding digit d.
template<int NBITS>
__device__ __forceinline__ u64 matchN(u32 d) {
    u64 m = ~0ull;
    #pragma unroll
    for (int bit = 0; bit < NBITS; ++bit) {
        u64 bl = __ballot((d >> bit) & 1u);
        m &= ((d >> bit) & 1u) ? bl : ~bl;
    }
    return m;
}

// ---------------------------------------------------------------------------
// Kernel 0: vectorized ch-0 extract. Dense float4 reads (R4 lesson: 84B-
// strided scalar reads are latency-bound at 1.8 TB/s; dense float4 ~6 TB/s).
// ---------------------------------------------------------------------------
__global__ __launch_bounds__(256) void extract_kernel(const float* __restrict__ lg,
                                                      float* __restrict__ planes) {
    const u32 gtid = blockIdx.x * 256 + threadIdx.x;   // [0, 262144)
    const float4* l4 = (const float4*)lg;
    #pragma unroll
    for (u32 it = 0; it < 21; ++it) {
        u32 g = it * 262144u + gtid;                   // [0, 5505024)
        float4 v = l4[g];
        u32 base = g * 4u;
        u32 k = (base + 20u) / 21u;                    // first px with ch0 >= base
        u32 pos = k * 21u - base;
        if (pos < 4u) {
            float val = (pos == 0u) ? v.x : (pos == 1u) ? v.y : (pos == 2u) ? v.z : v.w;
            planes[k] = val;
        }
    }
}

// ---------------------------------------------------------------------------
// Kernel 1: bilinear sample. R10: two-sweep plane staging — rows [0,65) then
// [64,128), 33.3 KB halves (R4-validated partition: point handled in the
// sweep containing x0i; x1<=x0+1 keeps all 4 taps in-half). LDS 68->37.4 KB
// -> 3 blocks/CU @ 512 thr = 24 waves/CU (was 16) on a latency-bound body.
// key = fp32 bits of |interp| (order-isomorphic, non-negative); element =
// (key<<16)|idx; LSD stability supplies the idx tie-break (jax.lax.top_k).
// fp contract OFF: bit-exact arithmetic required.
// ---------------------------------------------------------------------------
__global__ __launch_bounds__(512, 6) void sample_key_kernel(const float* __restrict__ planes,
                                                            const float2* __restrict__ coords,
                                                            u64* __restrict__ keys,
                                                            u32* __restrict__ hist) {
#pragma clang fp contract(off)
    __shared__ float pl[65 * 128];     // 33,280 B (row-half + boundary row)
    __shared__ u32 h[NB0];             // 4 KB
    const int tid = threadIdx.x;
    const int blk = blockIdx.x;
    DECODE_ST

    for (int i = tid; i < NB0; i += NTHR) h[i] = 0;
    float2 c[8];
    #pragma unroll
    for (int i = 0; i < 8; ++i) c[i] = coords[(size_t)s * Pp + t * TILE + i * NTHR + tid];
    const float4* p4 = (const float4*)(planes + (size_t)s * (Hh * Ww));
    float4* l4 = (float4*)pl;

    #pragma unroll 1
    for (int sweep = 0; sweep < 2; ++sweep) {
        if (sweep == 0) {
            for (int i = tid; i < 2080; i += NTHR) l4[i] = p4[i];          // rows [0,65)
        } else {
            __syncthreads();                                               // sweep-0 readers done
            for (int i = tid; i < 2048; i += NTHR) l4[i] = p4[2048 + i];   // rows [64,128)
        }
        __syncthreads();
        for (int i = 0; i < 8; ++i) {
            float xf = c[i].x * 127.0f;              // coords[...,0] -> H axis
            float yf = c[i].y * 127.0f;              // coords[...,1] -> W axis
            float x0 = floorf(xf), x1 = ceilf(xf);
            float y0 = floorf(yf), y1 = ceilf(yf);
            int x0i = (int)x0;
            if ((x0i >= 64 ? 1 : 0) != sweep) continue;   // exactly one sweep per point
            float mux = xf - x0;
            float muy = yf - y0;
            int rb  = x0i - sweep * 64;              // staged-row base
            int x1i = (int)x1 - sweep * 64;          // x1 <= x0+1 -> in staged half
            int y0i = (int)y0, y1i = (int)y1;
            float p1  = pl[rb  * Ww + y0i];
            float p2  = pl[x1i * Ww + y0i];
            float p3  = pl[rb  * Ww + y1i];
            float p4v = pl[x1i * Ww + y1i];
            float p12 = p1 * (1.0f - mux) + p2 * mux;
            float p34 = p3 * (1.0f - mux) + p4v * mux;
            float r   = p12 * (1.0f - muy) + p34 * muy;
            u32 kb = __float_as_uint(r) & 0x7fffffffu;   // |r| bits
            int idx = t * TILE + i * NTHR + tid;
            keys[(size_t)s * Pp + idx] = ((u64)kb << 16) | (u32)idx;
            atomicAdd(&h[kb & (NB0 - 1)], 1u);           // pass-0 digit (uniform)
        }
    }
    __syncthreads();
    const size_t hbase = ((size_t)s * TILES + t) * NB0;
    for (int d = tid; d < NB0; d += NTHR) hist[hbase + d] = h[d];
}

// ---------------------------------------------------------------------------
// hist64: per-wave privatized tables (8 waves x 1024 bins, uniform digit ->
// negligible collisions). Output layout [s][t][d] (tile-major, coalesced).
// ---------------------------------------------------------------------------
__global__ __launch_bounds__(512, 8) void hist64_kernel(const u64* __restrict__ in,
                                                        u32* __restrict__ hist, int shift) {
    __shared__ u32 h[8][NB0];          // 32 KB
    const int tid = threadIdx.x;
    const int w = tid >> 6;
    const int blk = blockIdx.x;
    DECODE_ST
    for (int i = tid; i < 8 * NB0; i += NTHR) ((u32*)h)[i] = 0;
    __syncthreads();
    const u64* src = in + (size_t)s * Pp + t * TILE;
    #pragma unroll 4
    for (int i = 0; i < 8; ++i) {
        u64 v = src[i * NTHR + tid];
        atomicAdd(&h[w][(u32)(v >> shift) & (NB0 - 1)], 1u);
    }
    __syncthreads();
    const size_t hbase = ((size_t)s * TILES + t) * NB0;
    for (int d = tid; d < NB0; d += NTHR) {
        u32 sum = 0;
        #pragma unroll
        for (int k = 0; k < 8; ++k) sum += h[k][d];
        hist[hbase + d] = sum;
    }
}

// hist32 stays 256-thr/4-table: pass-2 digit is SKEWED; more waves on shared
// tables would increase hot-bin atomic serialization.
__global__ __launch_bounds__(256) void hist32_kernel(const u32* __restrict__ in,
                                                     u32* __restrict__ hist) {
    __shared__ u32 h[4][NB2];          // 32 KB
    const int tid = threadIdx.x;
    const int w = tid >> 6;
    const int blk = blockIdx.x;
    DECODE_ST
    for (int i = tid; i < 4 * NB2; i += 256) ((u32*)h)[i] = 0;
    __syncthreads();
    const u32* src = in + (size_t)s * Pp + t * TILE;
    #pragma unroll 4
    for (int i = 0; i < 16; ++i) {
        u32 v = src[i * 256 + tid];
        atomicAdd(&h[w][(v >> 16) & (NB2 - 1)], 1u);   // 11-bit top digit
    }
    __syncthreads();
    const size_t hbase = ((size_t)s * TILES + t) * NB2;
    #pragma unroll
    for (int j = 0; j < NB2 / 256; ++j) {
        int d = j * 256 + tid;
        hist[hbase + d] = h[0][d] + h[1][d] + h[2][d] + h[3][d];
    }
}

// ---------------------------------------------------------------------------
// Offset derivation: raw per-tile hist [s][t][d] ->
//   off[s][d][t] = sum_{d'<d} segtot[d'] + sum_{t'<t} cnt[d][t']
// Seg tables staged in scan scratch (head of el, dead until phase B); dual
// block-scan packed in u64 (local count low, segment count high; no carry).
// ---------------------------------------------------------------------------
template<int NB>
__device__ __forceinline__ void fill_seg_tables(u32* sc1v, u32* sc2v,
                                                const u32* hb, int t, int tid) {
    for (int d = tid; d < NB; d += NTHR) {
        u32 tot = 0, pre = 0;
        #pragma unroll
        for (int tt = 0; tt < TILES; ++tt) {
            u32 cv = hb[tt * NB + d];       // coalesced, L2-hot
            tot += cv;
            pre += (tt < t) ? cv : 0;
        }
        sc1v[d] = tot;
        sc2v[d] = pre;
    }
}

// wh layout: [digit][8 waves] u16. dl[d] = off - local_start (mod 2^16, exact
// since Pp < 65536).
template<int NB>
__device__ __forceinline__ void block_scan(const u32* sc1v, const u32* sc2v,
                                           u16* wh, u16* dl, u64* aux,
                                           int tid, int lane, int w) {
    constexpr int DPB = NB / NTHR;          // digits per thread (2 or 4)
    const int d0 = tid * DPB;
    u32 dtot[DPB], gtot[DPB], gpre[DPB];
    u32 t8l = 0, t8g = 0;
    #pragma unroll
    for (int j = 0; j < DPB; ++j) {
        int d = d0 + j;
        u32 cv = 0;
        #pragma unroll
        for (int k = 0; k < 8; ++k) cv += wh[d * 8 + k];
        dtot[j] = cv; t8l += cv;
        gtot[j] = sc1v[d]; gpre[j] = sc2v[d]; t8g += gtot[j];
    }
    u64 own = ((u64)t8g << 32) | t8l;
    u64 sc = own;
    for (int o = 1; o < 64; o <<= 1) {
        u64 n = __shfl_up((unsigned long long)sc, o);
        if (lane >= o) sc += n;
    }
    if (lane == 63) aux[w] = sc;
    __syncthreads();
    if (tid == 0) {
        u64 run = 0;
        #pragma unroll
        for (int i = 0; i < 8; ++i) { u64 x = aux[i]; aux[i] = run; run += x; }
    }
    __syncthreads();
    u64 excl = sc - own + aux[w];
    u32 run_l = (u32)excl;                  // local exclusive base
    u32 run_g = (u32)(excl >> 32);          // segment digit-exclusive base
    #pragma unroll
    for (int j = 0; j < DPB; ++j) {
        int d = d0 + j;
        u32 ls = run_l;
        u32 g = run_g + gpre[j];            // off[s][d][t]
        dl[d] = (u16)(g - ls);
        u32 acc = ls;
        #pragma unroll
        for (int k = 0; k < 8; ++k) {
            u32 ck = wh[d * 8 + k];
            wh[d * 8 + k] = (u16)acc;
            acc += ck;
        }
        run_l += dtot[j];
        run_g += gtot[j];
    }
}

// ---------------------------------------------------------------------------
// Scatter (u64 passes 0,1): stable LDS reorder + run-contiguous global write.
// 512 thr, 8 els/thread -> 24 waves/CU. matchN once per element; cached
// ranks reused in phase B. COMPRESS (pass 1): emit u32 (key[36,47)<<16)|idx
// — bits [16,36) spent; halves pass-2 traffic.
// LDS: 32K el + 16K wh + 2K dl = 50.3 KB -> 3 blocks/CU.
// (R9 lesson: do NOT fuse next-pass hist in here — slab prologue+phase D
// cost ~2.5x the hist kernel they replaced.)
// ---------------------------------------------------------------------------
template<int SHIFT, bool COMPRESS>
__global__ __launch_bounds__(512, 6) void scatter64_kernel(const u64* __restrict__ in,
                                                           void* __restrict__ outbuf,
                                                           const u32* __restrict__ hist) {
    __shared__ u64 el[TILE];           // 32 KB (head = scan scratch pre-B)
    __shared__ u16 wh[NB0 * 8];        // 16 KB  [digit][wave]
    __shared__ u16 dl[NB0];            // 2 KB
    __shared__ u64 aux[8];
    const int tid = threadIdx.x;
    const int lane = tid & 63;
    const int w = tid >> 6;
    const int blk = blockIdx.x;
    DECODE_ST
    const u64* src = in + (size_t)s * Pp + t * TILE;

    for (int i = tid; i < NB0 * 4; i += NTHR) ((u32*)wh)[i] = 0;
    u64 v[8];
    #pragma unroll
    for (int i = 0; i < 8; ++i) v[i] = src[w * 512 + i * 64 + lane];
    fill_seg_tables<NB0>((u32*)el, (u32*)el + NB0, hist + (size_t)s * (TILES * NB0), t, tid);
    __syncthreads();

    const u64 ltmask = (1ull << lane) - 1ull;
    u32 dg[8], pk[8];
    volatile u16* vwh = wh;
    #pragma unroll 2
    for (int i = 0; i < 8; ++i) {
        u32 d = (u32)(v[i] >> SHIFT) & (NB0 - 1);
        u64 m = matchN<10>(d);
        u32 before = (u32)__popcll(m & ltmask);
        u32 cnt = (u32)__popcll(m);
        bool lead = (lane == __ffsll((unsigned long long)m) - 1);
        dg[i] = d;
        pk[i] = before | (cnt << 8) | (lead ? 0x10000u : 0u);
        if (lead) { u32 p = d * 8 + w; vwh[p] = (u16)(vwh[p] + cnt); }
    }
    __syncthreads();
    block_scan<NB0>((const u32*)el, (const u32*)el + NB0, wh, dl, aux, tid, lane, w);
    __syncthreads();

    for (int i = 0; i < 8; ++i) {
        u32 d = dg[i];
        u32 before = pk[i] & 0xffu;
        u32 base = vwh[d * 8 + w];
        el[base + before] = v[i];
        if (pk[i] & 0x10000u) vwh[d * 8 + w] = (u16)(base + ((pk[i] >> 8) & 0xffu));
    }
    __syncthreads();

    if (!COMPRESS) {
        u64* dst = (u64*)outbuf + (size_t)s * Pp;
        for (int i = 0; i < 8; ++i) {
            int pos = i * NTHR + tid;
            u64 e = el[pos];
            u32 d = (u32)(e >> SHIFT) & (NB0 - 1);
            u32 g = (u32)(u16)(pos + dl[d]);
            dst[g] = e;
        }
    } else {
        u32* dst = (u32*)outbuf + (size_t)s * Pp;
        for (int i = 0; i < 8; ++i) {
            int pos = i * NTHR + tid;
            u64 e = el[pos];
            u32 d = (u32)(e >> SHIFT) & (NB0 - 1);
            u32 g = (u32)(u16)(pos + dl[d]);
            dst[g] = ((u32)(e >> 36) << 16) | (u32)(e & 0xffffu);   // key[36,47) | idx
        }
    }
}

// ---------------------------------------------------------------------------
// Final scatter (u32, 11-bit top digit): rank -> g; emit out[s][g] =
// coords[s][idx] for g < K; fused extra_random copy into rows [K, P).
// LDS: 16K el32 + 32K wh + 4K dl = 53.3 KB -> 3 blocks/CU (159.9 <= 160).
// ---------------------------------------------------------------------------
__global__ __launch_bounds__(512, 6) void scatter32_final_kernel(const u32* __restrict__ in,
                                                                 const u32* __restrict__ hist,
                                                                 const float2* __restrict__ coords,
                                                                 const float2* __restrict__ extra,
                                                                 float2* __restrict__ out) {
    __shared__ u32 el32[TILE];         // 16 KB (head = scan scratch pre-B)
    __shared__ u16 wh[NB2 * 8];        // 32 KB
    __shared__ u16 dl[NB2];            // 4 KB
    __shared__ u64 aux[8];
    const int tid = threadIdx.x;
    const int lane = tid & 63;
    const int w = tid >> 6;
    const int blk = blockIdx.x;
    DECODE_ST
    const u32* src = in + (size_t)s * Pp + t * TILE;

    for (int i = tid; i < NB2 * 4; i += NTHR) ((u32*)wh)[i] = 0;
    u32 v[8];
    #pragma unroll
    for (int i = 0; i < 8; ++i) v[i] = src[w * 512 + i * 64 + lane];
    fill_seg_tables<NB2>((u32*)el32, (u32*)el32 + NB2, hist + (size_t)s * (TILES * NB2), t, tid);
    __syncthreads();

    const u64 ltmask = (1ull << lane) - 1ull;
    u32 dg[8], pk[8];
    volatile u16* vwh = wh;
    #pragma unroll 2
    for (int i = 0; i < 8; ++i) {
        u32 d = (v[i] >> 16) & (NB2 - 1);
        u64 m = matchN<11>(d);
        u32 before = (u32)__popcll(m & ltmask);
        u32 cnt = (u32)__popcll(m);
        bool lead = (lane == __ffsll((unsigned long long)m) - 1);
        dg[i] = d;
        pk[i] = before | (cnt << 8) | (lead ? 0x10000u : 0u);
        if (lead) { u32 p = d * 8 + w; vwh[p] = (u16)(vwh[p] + cnt); }
    }
    __syncthreads();
    block_scan<NB2>((const u32*)el32, (const u32*)el32 + NB2, wh, dl, aux, tid, lane, w);
    __syncthreads();

    for (int i = 0; i < 8; ++i) {
        u32 d = dg[i];
        u32 before = pk[i] & 0xffu;
        u32 base = vwh[d * 8 + w];
        el32[base + before] = v[i];
        if (pk[i] & 0x10000u) vwh[d * 8 + w] = (u16)(base + ((pk[i] >> 8) & 0xffu));
    }
    __syncthreads();

    const float2* cseg = coords + (size_t)s * Pp;
    float2* oseg = out + (size_t)s * Pp;
    for (int i = 0; i < 8; ++i) {
        int pos = i * NTHR + tid;
        u32 e = el32[pos];
        u32 d = (e >> 16) & (NB2 - 1);
        u32 g = (u32)(u16)(pos + dl[d]);
        if (g < Kk) oseg[g] = cseg[e & 0xffffu];
    }
    const float2* eseg = extra + (size_t)s * NR;
    float2* xseg = out + (size_t)s * Pp + Kk;
    #pragma unroll
    for (int i = 0; i < 2; ++i) {
        int p = t * 1024 + i * NTHR + tid;
        xseg[p] = eseg[p];
    }
}

extern "C" void kernel_launch(void* const* d_in, const int* in_sizes, int n_in,
                              void* d_out, int out_size, void* d_ws, size_t ws_size,
                              hipStream_t stream) {
    (void)in_sizes; (void)n_in; (void)out_size; (void)ws_size;
    const float*  logits = (const float*)d_in[0];   // (B,H,W,C) fp32
    const float2* coords = (const float2*)d_in[1];  // (B,P,2)  fp32
    const float2* extra  = (const float2*)d_in[2];  // (B,NR,2) fp32
    float2* out = (float2*)d_out;

    u64* buf0 = (u64*)d_ws;                          // 25.2 MB
    u64* buf1 = buf0 + (size_t)Bb * Pp;              // 25.2 MB (ping-pong)
    float* planes = (float*)buf1;                    // 4 MB; dead before pass-0 scatter writes buf1
    u32* histA = (u32*)d_out;                        // 3.1 MB pass 0/1 hist (d_out scratch; final pass overwrites all of out)
    u32* histB = (u32*)buf1;                         // pass-2 hist (6.3 MB); buf1 dead after pass-1 scatter

    // ch-0 extract (dense float4) -> compact planes
    extract_kernel<<<1024, 256, 0, stream>>>(logits, planes);
    // sample: planes,coords -> keys(buf0,u64) + pass-0 hist (10-bit)
    sample_key_kernel<<<NBLK, NTHR, 0, stream>>>(planes, coords, buf0, histA);
    // pass 0: bits [16,26)  buf0(u64) -> buf1(u64)
    scatter64_kernel<16, false><<<NBLK, NTHR, 0, stream>>>(buf0, buf1, histA);
    // pass 1: bits [26,36)  buf1(u64) -> buf0(u32 compressed: key[36,47)|idx)
    hist64_kernel<<<NBLK, NTHR, 0, stream>>>(buf1, histA, 26);
    scatter64_kernel<26, true><<<NBLK, NTHR, 0, stream>>>(buf1, buf0, histA);
    // pass 2: 11-bit top digit  buf0(u32) -> out (fused gather+emit+extra)
    hist32_kernel<<<NBLK, 256, 0, stream>>>((const u32*)buf0, histB);
    scatter32_final_kernel<<<NBLK, NTHR, 0, stream>>>((const u32*)buf0, histB, coords, extra, out);
}

// Round 11
// 259.816 us; speedup vs baseline: 1.1490x; 1.0972x over previous
//
#include <hip/hip_runtime.h>
#include <stdint.h>

#define Bb 64
#define Hh 128
#define Ww 128
#define Cc 21
#define Pp 49152          // NUM_SAMPLED
#define Kk 36864          // NUM_UNCERTAIN
#define NR 12288          // NUM_RANDOM

// Digit split 10/10/11 over key bits [16,47): passes 0,1 use 10-bit digits
// (write runs ~4); pass 2 gets the 11-bit exponent-dominated digit (skewed
// -> long runs -> coalesced writes).
#define NB0 1024          // pass 0/1 bins
#define NB2 2048          // pass 2 bins
#define TILE 4096         // elements per sort tile
#define TILES 12          // Pp / TILE
#define NBLK (Bb * TILES) // 768 blocks
#define NTHR 512          // 8 waves/block (R8: same LDS/tile, 2x waves/CU)

typedef uint32_t u32;
typedef uint64_t u64;
typedef unsigned short u16;

// XCD-affine decode: all TILES blocks of segment s have blk%8 == s%8 ->
// segment's r/w window stays in one XCD's L2. Heuristic only.
#define DECODE_ST const int s = blk & 63; const int t = blk >> 6;

// N-bit ballot digit-match: mask of lanes in this wave holding digit d.
// (Stable: rank derived from lane order, not atomic return order.)
template<int NBITS>
__device__ __forceinline__ u64 matchN(u32 d) {
    u64 m = ~0ull;
    #pragma unroll
    for (int bit = 0; bit < NBITS; ++bit) {
        u64 bl = __ballot((d >> bit) & 1u);
        m &= ((d >> bit) & 1u) ? bl : ~bl;
    }
    return m;
}

// ---------------------------------------------------------------------------
// Kernel 0: vectorized ch-0 extract. Dense 16B reads (R4 lesson: 84B-strided
// scalar reads are latency-bound at 1.8 TB/s; dense vector reads ~6 TB/s).
// R11: NON-TEMPORAL loads — logits is read-once (88 MB); keeping it out of
// L2 protects the planes working set (R10 measured 43 MB of plane re-fetch
// caused by streaming eviction).
// ---------------------------------------------------------------------------
__global__ __launch_bounds__(256) void extract_kernel(const float* __restrict__ lg,
                                                      float* __restrict__ planes) {
    const u32 gtid = blockIdx.x * 256 + threadIdx.x;   // [0, 262144)
    const u64* lp = (const u64*)lg;
    #pragma unroll
    for (u32 it = 0; it < 21; ++it) {
        u32 g = it * 262144u + gtid;                   // float4 index [0, 5505024)
        u64 a = __builtin_nontemporal_load(lp + 2 * (size_t)g);
        u64 b = __builtin_nontemporal_load(lp + 2 * (size_t)g + 1);
        u32 base = g * 4u;
        u32 k = (base + 20u) / 21u;                    // first px with ch0 >= base
        u32 pos = k * 21u - base;
        if (pos < 4u) {
            u32 bits = (pos == 0u) ? (u32)a : (pos == 1u) ? (u32)(a >> 32)
                     : (pos == 2u) ? (u32)b : (u32)(b >> 32);
            planes[k] = __uint_as_float(bits);         // monotone-dense writes
        }
    }
}

// ---------------------------------------------------------------------------
// Kernel 1: bilinear sample (64 KB compact plane staged via float4), key
// build, fused pass-0 (10-bit) hist. (R8 form — R10's two-sweep variant
// regressed +28 us and is reverted.) R11: coords loads NON-TEMPORAL (25 MB,
// no short-range reuse) to keep plane lines L2-resident.
// key = fp32 bits of |interp| (order-isomorphic, non-negative); element =
// (key<<16)|idx; LSD stability supplies the idx tie-break (jax.lax.top_k).
// fp contract OFF: bit-exact arithmetic required.
// ---------------------------------------------------------------------------
__global__ __launch_bounds__(512, 4) void sample_key_kernel(const float* __restrict__ planes,
                                                            const float2* __restrict__ coords,
                                                            u64* __restrict__ keys,
                                                            u32* __restrict__ hist) {
#pragma clang fp contract(off)
    __shared__ float pl[Hh * Ww];      // 64 KB
    __shared__ u32 h[NB0];             // 4 KB
    const int tid = threadIdx.x;
    const int blk = blockIdx.x;
    DECODE_ST

    for (int i = tid; i < NB0; i += NTHR) h[i] = 0;
    const float4* p4 = (const float4*)(planes + (size_t)s * (Hh * Ww));
    float4* l4 = (float4*)pl;
    #pragma unroll
    for (int i = 0; i < 8; ++i) l4[i * NTHR + tid] = p4[i * NTHR + tid];
    __syncthreads();

    #pragma unroll 4
    for (int i = 0; i < 8; ++i) {
        int idx = t * TILE + i * NTHR + tid;           // point index within segment
        int gid = s * Pp + idx;
        u64 cv = __builtin_nontemporal_load((const u64*)(coords + gid));
        float xf = __uint_as_float((u32)cv) * 127.0f;          // coords[...,0] -> H
        float yf = __uint_as_float((u32)(cv >> 32)) * 127.0f;  // coords[...,1] -> W
        float x0 = floorf(xf), x1 = ceilf(xf);
        float y0 = floorf(yf), y1 = ceilf(yf);
        float mux = xf - x0;
        float muy = yf - y0;
        int x0i = (int)x0, x1i = (int)x1, y0i = (int)y0, y1i = (int)y1;
        float p1  = pl[x0i * Ww + y0i];
        float p2  = pl[x1i * Ww + y0i];
        float p3  = pl[x0i * Ww + y1i];
        float p4v = pl[x1i * Ww + y1i];
        float p12 = p1 * (1.0f - mux) + p2 * mux;
        float p34 = p3 * (1.0f - mux) + p4v * mux;
        float r   = p12 * (1.0f - muy) + p34 * muy;
        u32 kb = __float_as_uint(r) & 0x7fffffffu;     // |r| bits
        keys[gid] = ((u64)kb << 16) | (u32)idx;
        atomicAdd(&h[kb & (NB0 - 1)], 1u);             // pass-0 digit (uniform)
    }
    __syncthreads();
    const size_t hbase = ((size_t)s * TILES + t) * NB0;
    for (int d = tid; d < NB0; d += NTHR) hist[hbase + d] = h[d];
}

// ---------------------------------------------------------------------------
// hist64: per-wave privatized tables (8 waves x 1024 bins, uniform digit ->
// negligible collisions). Output layout [s][t][d] (tile-major, coalesced).
// ---------------------------------------------------------------------------
__global__ __launch_bounds__(512, 8) void hist64_kernel(const u64* __restrict__ in,
                                                        u32* __restrict__ hist, int shift) {
    __shared__ u32 h[8][NB0];          // 32 KB
    const int tid = threadIdx.x;
    const int w = tid >> 6;
    const int blk = blockIdx.x;
    DECODE_ST
    for (int i = tid; i < 8 * NB0; i += NTHR) ((u32*)h)[i] = 0;
    __syncthreads();
    const u64* src = in + (size_t)s * Pp + t * TILE;
    #pragma unroll 4
    for (int i = 0; i < 8; ++i) {
        u64 v = src[i * NTHR + tid];
        atomicAdd(&h[w][(u32)(v >> shift) & (NB0 - 1)], 1u);
    }
    __syncthreads();
    const size_t hbase = ((size_t)s * TILES + t) * NB0;
    for (int d = tid; d < NB0; d += NTHR) {
        u32 sum = 0;
        #pragma unroll
        for (int k = 0; k < 8; ++k) sum += h[k][d];
        hist[hbase + d] = sum;
    }
}

// hist32 stays 256-thr/4-table: pass-2 digit is SKEWED; more waves on shared
// tables would increase hot-bin atomic serialization.
__global__ __launch_bounds__(256) void hist32_kernel(const u32* __restrict__ in,
                                                     u32* __restrict__ hist) {
    __shared__ u32 h[4][NB2];          // 32 KB
    const int tid = threadIdx.x;
    const int w = tid >> 6;
    const int blk = blockIdx.x;
    DECODE_ST
    for (int i = tid; i < 4 * NB2; i += 256) ((u32*)h)[i] = 0;
    __syncthreads();
    const u32* src = in + (size_t)s * Pp + t * TILE;
    #pragma unroll 4
    for (int i = 0; i < 16; ++i) {
        u32 v = src[i * 256 + tid];
        atomicAdd(&h[w][(v >> 16) & (NB2 - 1)], 1u);   // 11-bit top digit
    }
    __syncthreads();
    const size_t hbase = ((size_t)s * TILES + t) * NB2;
    #pragma unroll
    for (int j = 0; j < NB2 / 256; ++j) {
        int d = j * 256 + tid;
        hist[hbase + d] = h[0][d] + h[1][d] + h[2][d] + h[3][d];
    }
}

// ---------------------------------------------------------------------------
// Offset derivation: raw per-tile hist [s][t][d] ->
//   off[s][d][t] = sum_{d'<d} segtot[d'] + sum_{t'<t} cnt[d][t']
// Seg tables staged in scan scratch (head of el, dead until phase B); dual
// block-scan packed in u64 (local count low, segment count high; no carry).
// ---------------------------------------------------------------------------
template<int NB>
__device__ __forceinline__ void fill_seg_tables(u32* sc1v, u32* sc2v,
                                                const u32* hb, int t, int tid) {
    for (int d = tid; d < NB; d += NTHR) {
        u32 tot = 0, pre = 0;
        #pragma unroll
        for (int tt = 0; tt < TILES; ++tt) {
            u32 cv = hb[tt * NB + d];       // coalesced, L2-hot
            tot += cv;
            pre += (tt < t) ? cv : 0;
        }
        sc1v[d] = tot;
        sc2v[d] = pre;
    }
}

// wh layout: [digit][8 waves] u16. dl[d] = off - local_start (mod 2^16, exact
// since Pp < 65536).
template<int NB>
__device__ __forceinline__ void block_scan(const u32* sc1v, const u32* sc2v,
                                           u16* wh, u16* dl, u64* aux,
                                           int tid, int lane, int w) {
    constexpr int DPB = NB / NTHR;          // digits per thread (2 or 4)
    const int d0 = tid * DPB;
    u32 dtot[DPB], gtot[DPB], gpre[DPB];
    u32 t8l = 0, t8g = 0;
    #pragma unroll
    for (int j = 0; j < DPB; ++j) {
        int d = d0 + j;
        u32 cv = 0;
        #pragma unroll
        for (int k = 0; k < 8; ++k) cv += wh[d * 8 + k];
        dtot[j] = cv; t8l += cv;
        gtot[j] = sc1v[d]; gpre[j] = sc2v[d]; t8g += gtot[j];
    }
    u64 own = ((u64)t8g << 32) | t8l;
    u64 sc = own;
    for (int o = 1; o < 64; o <<= 1) {
        u64 n = __shfl_up((unsigned long long)sc, o);
        if (lane >= o) sc += n;
    }
    if (lane == 63) aux[w] = sc;
    __syncthreads();
    if (tid == 0) {
        u64 run = 0;
        #pragma unroll
        for (int i = 0; i < 8; ++i) { u64 x = aux[i]; aux[i] = run; run += x; }
    }
    __syncthreads();
    u64 excl = sc - own + aux[w];
    u32 run_l = (u32)excl;                  // local exclusive base
    u32 run_g = (u32)(excl >> 32);          // segment digit-exclusive base
    #pragma unroll
    for (int j = 0; j < DPB; ++j) {
        int d = d0 + j;
        u32 ls = run_l;
        u32 g = run_g + gpre[j];            // off[s][d][t]
        dl[d] = (u16)(g - ls);
        u32 acc = ls;
        #pragma unroll
        for (int k = 0; k < 8; ++k) {
            u32 ck = wh[d * 8 + k];
            wh[d * 8 + k] = (u16)acc;
            acc += ck;
        }
        run_l += dtot[j];
        run_g += gtot[j];
    }
}

// ---------------------------------------------------------------------------
// Scatter (u64 passes 0,1): stable LDS reorder + run-contiguous global write.
// 512 thr, 8 els/thread -> 24 waves/CU. matchN once per element; cached
// ranks reused in phase B. COMPRESS (pass 1): emit u32 (key[36,47)<<16)|idx
// — bits [16,36) spent; halves pass-2 traffic.
// LDS: 32K el + 16K wh + 2K dl = 50.3 KB -> 3 blocks/CU.
// (R9 lesson: do NOT fuse next-pass hist in here — slab prologue+phase D
// cost ~2.5x the hist kernel they replaced.)
// ---------------------------------------------------------------------------
template<int SHIFT, bool COMPRESS>
__global__ __launch_bounds__(512, 6) void scatter64_kernel(const u64* __restrict__ in,
                                                           void* __restrict__ outbuf,
                                                           const u32* __restrict__ hist) {
    __shared__ u64 el[TILE];           // 32 KB (head = scan scratch pre-B)
    __shared__ u16 wh[NB0 * 8];        // 16 KB  [digit][wave]
    __shared__ u16 dl[NB0];            // 2 KB
    __shared__ u64 aux[8];
    const int tid = threadIdx.x;
    const int lane = tid & 63;
    const int w = tid >> 6;
    const int blk = blockIdx.x;
    DECODE_ST
    const u64* src = in + (size_t)s * Pp + t * TILE;

    for (int i = tid; i < NB0 * 4; i += NTHR) ((u32*)wh)[i] = 0;
    u64 v[8];
    #pragma unroll
    for (int i = 0; i < 8; ++i) v[i] = src[w * 512 + i * 64 + lane];
    fill_seg_tables<NB0>((u32*)el, (u32*)el + NB0, hist + (size_t)s * (TILES * NB0), t, tid);
    __syncthreads();

    const u64 ltmask = (1ull << lane) - 1ull;
    u32 dg[8], pk[8];
    volatile u16* vwh = wh;
    #pragma unroll 2
    for (int i = 0; i < 8; ++i) {
        u32 d = (u32)(v[i] >> SHIFT) & (NB0 - 1);
        u64 m = matchN<10>(d);
        u32 before = (u32)__popcll(m & ltmask);
        u32 cnt = (u32)__popcll(m);
        bool lead = (lane == __ffsll((unsigned long long)m) - 1);
        dg[i] = d;
        pk[i] = before | (cnt << 8) | (lead ? 0x10000u : 0u);
        if (lead) { u32 p = d * 8 + w; vwh[p] = (u16)(vwh[p] + cnt); }
    }
    __syncthreads();
    block_scan<NB0>((const u32*)el, (const u32*)el + NB0, wh, dl, aux, tid, lane, w);
    __syncthreads();

    for (int i = 0; i < 8; ++i) {
        u32 d = dg[i];
        u32 before = pk[i] & 0xffu;
        u32 base = vwh[d * 8 + w];
        el[base + before] = v[i];
        if (pk[i] & 0x10000u) vwh[d * 8 + w] = (u16)(base + ((pk[i] >> 8) & 0xffu));
    }
    __syncthreads();

    if (!COMPRESS) {
        u64* dst = (u64*)outbuf + (size_t)s * Pp;
        for (int i = 0; i < 8; ++i) {
            int pos = i * NTHR + tid;
            u64 e = el[pos];
            u32 d = (u32)(e >> SHIFT) & (NB0 - 1);
            u32 g = (u32)(u16)(pos + dl[d]);
            dst[g] = e;
        }
    } else {
        u32* dst = (u32*)outbuf + (size_t)s * Pp;
        for (int i = 0; i < 8; ++i) {
            int pos = i * NTHR + tid;
            u64 e = el[pos];
            u32 d = (u32)(e >> SHIFT) & (NB0 - 1);
            u32 g = (u32)(u16)(pos + dl[d]);
            dst[g] = ((u32)(e >> 36) << 16) | (u32)(e & 0xffffu);   // key[36,47) | idx
        }
    }
}

// ---------------------------------------------------------------------------
// Final scatter (u32, 11-bit top digit): rank -> g; emit out[s][g] =
// coords[s][idx] for g < K; fused extra_random copy into rows [K, P).
// LDS: 16K el32 + 32K wh + 4K dl = 53.3 KB -> 3 blocks/CU (159.9 <= 160).
// coords gathers stay NORMAL (intra-line L2 reuse: 8 coords/line, each idx
// touched once -> NT would force line re-fetch).
// ---------------------------------------------------------------------------
__global__ __launch_bounds__(512, 6) void scatter32_final_kernel(const u32* __restrict__ in,
                                                                 const u32* __restrict__ hist,
                                                                 const float2* __restrict__ coords,
                                                                 const float2* __restrict__ extra,
                                                                 float2* __restrict__ out) {
    __shared__ u32 el32[TILE];         // 16 KB (head = scan scratch pre-B)
    __shared__ u16 wh[NB2 * 8];        // 32 KB
    __shared__ u16 dl[NB2];            // 4 KB
    __shared__ u64 aux[8];
    const int tid = threadIdx.x;
    const int lane = tid & 63;
    const int w = tid >> 6;
    const int blk = blockIdx.x;
    DECODE_ST
    const u32* src = in + (size_t)s * Pp + t * TILE;

    for (int i = tid; i < NB2 * 4; i += NTHR) ((u32*)wh)[i] = 0;
    u32 v[8];
    #pragma unroll
    for (int i = 0; i < 8; ++i) v[i] = src[w * 512 + i * 64 + lane];
    fill_seg_tables<NB2>((u32*)el32, (u32*)el32 + NB2, hist + (size_t)s * (TILES * NB2), t, tid);
    __syncthreads();

    const u64 ltmask = (1ull << lane) - 1ull;
    u32 dg[8], pk[8];
    volatile u16* vwh = wh;
    #pragma unroll 2
    for (int i = 0; i < 8; ++i) {
        u32 d = (v[i] >> 16) & (NB2 - 1);
        u64 m = matchN<11>(d);
        u32 before = (u32)__popcll(m & ltmask);
        u32 cnt = (u32)__popcll(m);
        bool lead = (lane == __ffsll((unsigned long long)m) - 1);
        dg[i] = d;
        pk[i] = before | (cnt << 8) | (lead ? 0x10000u : 0u);
        if (lead) { u32 p = d * 8 + w; vwh[p] = (u16)(vwh[p] + cnt); }
    }
    __syncthreads();
    block_scan<NB2>((const u32*)el32, (const u32*)el32 + NB2, wh, dl, aux, tid, lane, w);
    __syncthreads();

    for (int i = 0; i < 8; ++i) {
        u32 d = dg[i];
        u32 before = pk[i] & 0xffu;
        u32 base = vwh[d * 8 + w];
        el32[base + before] = v[i];
        if (pk[i] & 0x10000u) vwh[d * 8 + w] = (u16)(base + ((pk[i] >> 8) & 0xffu));
    }
    __syncthreads();

    const float2* cseg = coords + (size_t)s * Pp;
    float2* oseg = out + (size_t)s * Pp;
    for (int i = 0; i < 8; ++i) {
        int pos = i * NTHR + tid;
        u32 e = el32[pos];
        u32 d = (e >> 16) & (NB2 - 1);
        u32 g = (u32)(u16)(pos + dl[d]);
        if (g < Kk) oseg[g] = cseg[e & 0xffffu];
    }
    const float2* eseg = extra + (size_t)s * NR;
    float2* xseg = out + (size_t)s * Pp + Kk;
    #pragma unroll
    for (int i = 0; i < 2; ++i) {
        int p = t * 1024 + i * NTHR + tid;
        xseg[p] = eseg[p];
    }
}

extern "C" void kernel_launch(void* const* d_in, const int* in_sizes, int n_in,
                              void* d_out, int out_size, void* d_ws, size_t ws_size,
                              hipStream_t stream) {
    (void)in_sizes; (void)n_in; (void)out_size; (void)ws_size;
    const float*  logits = (const float*)d_in[0];   // (B,H,W,C) fp32
    const float2* coords = (const float2*)d_in[1];  // (B,P,2)  fp32
    const float2* extra  = (const float2*)d_in[2];  // (B,NR,2) fp32
    float2* out = (float2*)d_out;

    u64* buf0 = (u64*)d_ws;                          // 25.2 MB
    u64* buf1 = buf0 + (size_t)Bb * Pp;              // 25.2 MB (ping-pong)
    float* planes = (float*)buf1;                    // 4 MB; dead before pass-0 scatter writes buf1
    u32* histA = (u32*)d_out;                        // 3.1 MB pass 0/1 hist (d_out scratch; final pass overwrites all of out)
    u32* histB = (u32*)buf1;                         // pass-2 hist (6.3 MB); buf1 dead after pass-1 scatter

    // ch-0 extract (dense 16B NT reads) -> compact planes
    extract_kernel<<<1024, 256, 0, stream>>>(logits, planes);
    // sample: planes,coords(NT) -> keys(buf0,u64) + pass-0 hist (10-bit)
    sample_key_kernel<<<NBLK, NTHR, 0, stream>>>(planes, coords, buf0, histA);
    // pass 0: bits [16,26)  buf0(u64) -> buf1(u64)
    scatter64_kernel<16, false><<<NBLK, NTHR, 0, stream>>>(buf0, buf1, histA);
    // pass 1: bits [26,36)  buf1(u64) -> buf0(u32 compressed: key[36,47)|idx)
    hist64_kernel<<<NBLK, NTHR, 0, stream>>>(buf1, histA, 26);
    scatter64_kernel<26, true><<<NBLK, NTHR, 0, stream>>>(buf1, buf0, histA);
    // pass 2: 11-bit top digit  buf0(u32) -> out (fused gather+emit+extra)
    hist32_kernel<<<NBLK, 256, 0, stream>>>((const u32*)buf0, histB);
    scatter32_final_kernel<<<NBLK, NTHR, 0, stream>>>((const u32*)buf0, histB, coords, extra, out);
}

// Round 12
// 256.698 us; speedup vs baseline: 1.1629x; 1.0121x over previous
//
#include <hip/hip_runtime.h>
#include <stdint.h>

#define Bb 64
#define Hh 128
#define Ww 128
#define Cc 21
#define Pp 49152          // NUM_SAMPLED
#define Kk 36864          // NUM_UNCERTAIN
#define NR 12288          // NUM_RANDOM

// Digit split 10/10/11 over key bits [16,47): passes 0,1 use 10-bit digits
// (write runs ~4); pass 2 gets the 11-bit exponent-dominated digit (skewed
// -> long runs -> coalesced writes).
#define NB0 1024          // pass 0/1 bins
#define NB2 2048          // pass 2 bins
#define TILE 4096         // elements per sort tile
#define TILES 12          // Pp / TILE
#define NBLK (Bb * TILES) // 768 blocks
#define NTHR 512          // 8 waves/block (R8: same LDS/tile, 2x waves/CU)

typedef uint32_t u32;
typedef uint64_t u64;
typedef unsigned short u16;

// XCD-affine decode: all TILES blocks of segment s have blk%8 == s%8 ->
// segment's r/w window stays in one XCD's L2. Heuristic only.
#define DECODE_ST const int s = blk & 63; const int t = blk >> 6;

// N-bit ballot digit-match: mask of lanes in this wave holding digit d.
// (Stable: rank derived from lane order, not atomic return order.)
template<int NBITS>
__device__ __forceinline__ u64 matchN(u32 d) {
    u64 m = ~0ull;
    #pragma unroll
    for (int bit = 0; bit < NBITS; ++bit) {
        u64 bl = __ballot((d >> bit) & 1u);
        m &= ((d >> bit) & 1u) ? bl : ~bl;
    }
    return m;
}

// ---------------------------------------------------------------------------
// Kernel 0: vectorized ch-0 extract. Dense float4 reads (R4 lesson: 84B-
// strided scalar reads are latency-bound at 1.8 TB/s; dense float4 ~6 TB/s).
// ---------------------------------------------------------------------------
__global__ __launch_bounds__(256) void extract_kernel(const float* __restrict__ lg,
                                                      float* __restrict__ planes) {
    const u32 gtid = blockIdx.x * 256 + threadIdx.x;   // [0, 262144)
    const float4* l4 = (const float4*)lg;
    #pragma unroll
    for (u32 it = 0; it < 21; ++it) {
        u32 g = it * 262144u + gtid;                   // [0, 5505024)
        float4 v = l4[g];
        u32 base = g * 4u;
        u32 k = (base + 20u) / 21u;                    // first px with ch0 >= base
        u32 pos = k * 21u - base;
        if (pos < 4u) {
            float val = (pos == 0u) ? v.x : (pos == 1u) ? v.y : (pos == 2u) ? v.z : v.w;
            planes[k] = val;
        }
    }
}

// ---------------------------------------------------------------------------
// Kernel 1: bilinear sample (64 KB compact plane staged via float4), key
// build, fused pass-0 (10-bit) hist. (R8 form — the measured optimum; R10's
// two-sweep and R11's NT variants were null-or-negative and are dropped.)
// key = fp32 bits of |interp| (order-isomorphic, non-negative); element =
// (key<<16)|idx; LSD stability supplies the idx tie-break (jax.lax.top_k).
// fp contract OFF: bit-exact arithmetic required.
// ---------------------------------------------------------------------------
__global__ __launch_bounds__(512, 4) void sample_key_kernel(const float* __restrict__ planes,
                                                            const float2* __restrict__ coords,
                                                            u64* __restrict__ keys,
                                                            u32* __restrict__ hist) {
#pragma clang fp contract(off)
    __shared__ float pl[Hh * Ww];      // 64 KB
    __shared__ u32 h[NB0];             // 4 KB
    const int tid = threadIdx.x;
    const int blk = blockIdx.x;
    DECODE_ST

    for (int i = tid; i < NB0; i += NTHR) h[i] = 0;
    const float4* p4 = (const float4*)(planes + (size_t)s * (Hh * Ww));
    float4* l4 = (float4*)pl;
    #pragma unroll
    for (int i = 0; i < 8; ++i) l4[i * NTHR + tid] = p4[i * NTHR + tid];
    __syncthreads();

    #pragma unroll 4
    for (int i = 0; i < 8; ++i) {
        int idx = t * TILE + i * NTHR + tid;           // point index within segment
        int gid = s * Pp + idx;
        float2 c = coords[gid];
        float xf = c.x * 127.0f;                       // coords[...,0] -> H axis
        float yf = c.y * 127.0f;                       // coords[...,1] -> W axis
        float x0 = floorf(xf), x1 = ceilf(xf);
        float y0 = floorf(yf), y1 = ceilf(yf);
        float mux = xf - x0;
        float muy = yf - y0;
        int x0i = (int)x0, x1i = (int)x1, y0i = (int)y0, y1i = (int)y1;
        float p1  = pl[x0i * Ww + y0i];
        float p2  = pl[x1i * Ww + y0i];
        float p3  = pl[x0i * Ww + y1i];
        float p4v = pl[x1i * Ww + y1i];
        float p12 = p1 * (1.0f - mux) + p2 * mux;
        float p34 = p3 * (1.0f - mux) + p4v * mux;
        float r   = p12 * (1.0f - muy) + p34 * muy;
        u32 kb = __float_as_uint(r) & 0x7fffffffu;     // |r| bits
        keys[gid] = ((u64)kb << 16) | (u32)idx;
        atomicAdd(&h[kb & (NB0 - 1)], 1u);             // pass-0 digit (uniform)
    }
    __syncthreads();
    const size_t hbase = ((size_t)s * TILES + t) * NB0;
    for (int d = tid; d < NB0; d += NTHR) hist[hbase + d] = h[d];
}

// ---------------------------------------------------------------------------
// hist64: per-wave privatized tables (8 waves x 1024 bins, uniform digit ->
// negligible collisions). Output layout [s][t][d] (tile-major, coalesced).
// ---------------------------------------------------------------------------
__global__ __launch_bounds__(512, 8) void hist64_kernel(const u64* __restrict__ in,
                                                        u32* __restrict__ hist, int shift) {
    __shared__ u32 h[8][NB0];          // 32 KB
    const int tid = threadIdx.x;
    const int w = tid >> 6;
    const int blk = blockIdx.x;
    DECODE_ST
    for (int i = tid; i < 8 * NB0; i += NTHR) ((u32*)h)[i] = 0;
    __syncthreads();
    const u64* src = in + (size_t)s * Pp + t * TILE;
    #pragma unroll 4
    for (int i = 0; i < 8; ++i) {
        u64 v = src[i * NTHR + tid];
        atomicAdd(&h[w][(u32)(v >> shift) & (NB0 - 1)], 1u);
    }
    __syncthreads();
    const size_t hbase = ((size_t)s * TILES + t) * NB0;
    for (int d = tid; d < NB0; d += NTHR) {
        u32 sum = 0;
        #pragma unroll
        for (int k = 0; k < 8; ++k) sum += h[k][d];
        hist[hbase + d] = sum;
    }
}

// ---------------------------------------------------------------------------
// hist32 (pass 2): R12 — 512 thr with 8 per-wave tables of PACKED u16 pairs
// (two adjacent digits share a u32; carry impossible: per-(wave,digit) count
// <= 512 els). Same 32 KB LDS, per-wave privatization preserved, but
// 8 waves/block -> 4 blocks/CU = 32 waves/CU (was ~20) and 8 els/thread
// (was 16) on a latency-bound body.
// ---------------------------------------------------------------------------
__global__ __launch_bounds__(512, 8) void hist32_kernel(const u32* __restrict__ in,
                                                        u32* __restrict__ hist) {
    __shared__ u32 h[8][NB2 / 2];      // 32 KB: [wave][digit-pair] packed u16
    const int tid = threadIdx.x;
    const int w = tid >> 6;
    const int blk = blockIdx.x;
    DECODE_ST
    for (int i = tid; i < 8 * (NB2 / 2); i += NTHR) ((u32*)h)[i] = 0;
    __syncthreads();
    const u32* src = in + (size_t)s * Pp + t * TILE;
    #pragma unroll 4
    for (int i = 0; i < 8; ++i) {
        u32 v = src[i * NTHR + tid];
        u32 d = (v >> 16) & (NB2 - 1);                 // 11-bit top digit
        atomicAdd(&h[w][d >> 1], 1u << ((d & 1) * 16));
    }
    __syncthreads();
    const size_t hbase = ((size_t)s * TILES + t) * NB2;
    for (int d = tid; d < NB2; d += NTHR) {
        u32 sum = 0;
        #pragma unroll
        for (int k = 0; k < 8; ++k) sum += (h[k][d >> 1] >> ((d & 1) * 16)) & 0xffffu;
        hist[hbase + d] = sum;
    }
}

// ---------------------------------------------------------------------------
// Offset derivation: raw per-tile hist [s][t][d] ->
//   off[s][d][t] = sum_{d'<d} segtot[d'] + sum_{t'<t} cnt[d][t']
// Seg tables staged in scan scratch (head of el, dead until phase B); dual
// block-scan packed in u64 (local count low, segment count high; no carry).
// ---------------------------------------------------------------------------
template<int NB>
__device__ __forceinline__ void fill_seg_tables(u32* sc1v, u32* sc2v,
                                                const u32* hb, int t, int tid) {
    for (int d = tid; d < NB; d += NTHR) {
        u32 tot = 0, pre = 0;
        #pragma unroll
        for (int tt = 0; tt < TILES; ++tt) {
            u32 cv = hb[tt * NB + d];       // coalesced, L2-hot
            tot += cv;
            pre += (tt < t) ? cv : 0;
        }
        sc1v[d] = tot;
        sc2v[d] = pre;
    }
}

// wh layout: [digit][8 waves] u16. dl[d] = off - local_start (mod 2^16, exact
// since Pp < 65536).
template<int NB>
__device__ __forceinline__ void block_scan(const u32* sc1v, const u32* sc2v,
                                           u16* wh, u16* dl, u64* aux,
                                           int tid, int lane, int w) {
    constexpr int DPB = NB / NTHR;          // digits per thread (2 or 4)
    const int d0 = tid * DPB;
    u32 dtot[DPB], gtot[DPB], gpre[DPB];
    u32 t8l = 0, t8g = 0;
    #pragma unroll
    for (int j = 0; j < DPB; ++j) {
        int d = d0 + j;
        u32 cv = 0;
        #pragma unroll
        for (int k = 0; k < 8; ++k) cv += wh[d * 8 + k];
        dtot[j] = cv; t8l += cv;
        gtot[j] = sc1v[d]; gpre[j] = sc2v[d]; t8g += gtot[j];
    }
    u64 own = ((u64)t8g << 32) | t8l;
    u64 sc = own;
    for (int o = 1; o < 64; o <<= 1) {
        u64 n = __shfl_up((unsigned long long)sc, o);
        if (lane >= o) sc += n;
    }
    if (lane == 63) aux[w] = sc;
    __syncthreads();
    if (tid == 0) {
        u64 run = 0;
        #pragma unroll
        for (int i = 0; i < 8; ++i) { u64 x = aux[i]; aux[i] = run; run += x; }
    }
    __syncthreads();
    u64 excl = sc - own + aux[w];
    u32 run_l = (u32)excl;                  // local exclusive base
    u32 run_g = (u32)(excl >> 32);          // segment digit-exclusive base
    #pragma unroll
    for (int j = 0; j < DPB; ++j) {
        int d = d0 + j;
        u32 ls = run_l;
        u32 g = run_g + gpre[j];            // off[s][d][t]
        dl[d] = (u16)(g - ls);
        u32 acc = ls;
        #pragma unroll
        for (int k = 0; k < 8; ++k) {
            u32 ck = wh[d * 8 + k];
            wh[d * 8 + k] = (u16)acc;
            acc += ck;
        }
        run_l += dtot[j];
        run_g += gtot[j];
    }
}

// ---------------------------------------------------------------------------
// Scatter (u64 passes 0,1): stable LDS reorder + run-contiguous global write.
// 512 thr, 8 els/thread -> 24 waves/CU. matchN once per element; cached
// ranks reused in phase B. COMPRESS (pass 1): emit u32 (key[36,47)<<16)|idx
// — bits [16,36) spent; halves pass-2 traffic.
// LDS: 32K el + 16K wh + 2K dl = 50.3 KB -> 3 blocks/CU.
// (R9 lesson: do NOT fuse next-pass hist in here — slab prologue+phase D
// cost ~2.5x the hist kernel they replaced.)
// ---------------------------------------------------------------------------
template<int SHIFT, bool COMPRESS>
__global__ __launch_bounds__(512, 6) void scatter64_kernel(const u64* __restrict__ in,
                                                           void* __restrict__ outbuf,
                                                           const u32* __restrict__ hist) {
    __shared__ u64 el[TILE];           // 32 KB (head = scan scratch pre-B)
    __shared__ u16 wh[NB0 * 8];        // 16 KB  [digit][wave]
    __shared__ u16 dl[NB0];            // 2 KB
    __shared__ u64 aux[8];
    const int tid = threadIdx.x;
    const int lane = tid & 63;
    const int w = tid >> 6;
    const int blk = blockIdx.x;
    DECODE_ST
    const u64* src = in + (size_t)s * Pp + t * TILE;

    for (int i = tid; i < NB0 * 4; i += NTHR) ((u32*)wh)[i] = 0;
    u64 v[8];
    #pragma unroll
    for (int i = 0; i < 8; ++i) v[i] = src[w * 512 + i * 64 + lane];
    fill_seg_tables<NB0>((u32*)el, (u32*)el + NB0, hist + (size_t)s * (TILES * NB0), t, tid);
    __syncthreads();

    const u64 ltmask = (1ull << lane) - 1ull;
    u32 dg[8], pk[8];
    volatile u16* vwh = wh;
    #pragma unroll 2
    for (int i = 0; i < 8; ++i) {
        u32 d = (u32)(v[i] >> SHIFT) & (NB0 - 1);
        u64 m = matchN<10>(d);
        u32 before = (u32)__popcll(m & ltmask);
        u32 cnt = (u32)__popcll(m);
        bool lead = (lane == __ffsll((unsigned long long)m) - 1);
        dg[i] = d;
        pk[i] = before | (cnt << 8) | (lead ? 0x10000u : 0u);
        if (lead) { u32 p = d * 8 + w; vwh[p] = (u16)(vwh[p] + cnt); }
    }
    __syncthreads();
    block_scan<NB0>((const u32*)el, (const u32*)el + NB0, wh, dl, aux, tid, lane, w);
    __syncthreads();

    for (int i = 0; i < 8; ++i) {
        u32 d = dg[i];
        u32 before = pk[i] & 0xffu;
        u32 base = vwh[d * 8 + w];
        el[base + before] = v[i];
        if (pk[i] & 0x10000u) vwh[d * 8 + w] = (u16)(base + ((pk[i] >> 8) & 0xffu));
    }
    __syncthreads();

    if (!COMPRESS) {
        u64* dst = (u64*)outbuf + (size_t)s * Pp;
        for (int i = 0; i < 8; ++i) {
            int pos = i * NTHR + tid;
            u64 e = el[pos];
            u32 d = (u32)(e >> SHIFT) & (NB0 - 1);
            u32 g = (u32)(u16)(pos + dl[d]);
            dst[g] = e;
        }
    } else {
        u32* dst = (u32*)outbuf + (size_t)s * Pp;
        for (int i = 0; i < 8; ++i) {
            int pos = i * NTHR + tid;
            u64 e = el[pos];
            u32 d = (u32)(e >> SHIFT) & (NB0 - 1);
            u32 g = (u32)(u16)(pos + dl[d]);
            dst[g] = ((u32)(e >> 36) << 16) | (u32)(e & 0xffffu);   // key[36,47) | idx
        }
    }
}

// ---------------------------------------------------------------------------
// Final scatter (u32, 11-bit top digit): rank -> g; emit out[s][g] =
// coords[s][idx] for g < K; fused extra_random copy into rows [K, P).
// LDS: 16K el32 + 32K wh + 4K dl = 53.3 KB -> 3 blocks/CU (159.9 <= 160).
// ---------------------------------------------------------------------------
__global__ __launch_bounds__(512, 6) void scatter32_final_kernel(const u32* __restrict__ in,
                                                                 const u32* __restrict__ hist,
                                                                 const float2* __restrict__ coords,
                                                                 const float2* __restrict__ extra,
                                                                 float2* __restrict__ out) {
    __shared__ u32 el32[TILE];         // 16 KB (head = scan scratch pre-B)
    __shared__ u16 wh[NB2 * 8];        // 32 KB
    __shared__ u16 dl[NB2];            // 4 KB
    __shared__ u64 aux[8];
    const int tid = threadIdx.x;
    const int lane = tid & 63;
    const int w = tid >> 6;
    const int blk = blockIdx.x;
    DECODE_ST
    const u32* src = in + (size_t)s * Pp + t * TILE;

    for (int i = tid; i < NB2 * 4; i += NTHR) ((u32*)wh)[i] = 0;
    u32 v[8];
    #pragma unroll
    for (int i = 0; i < 8; ++i) v[i] = src[w * 512 + i * 64 + lane];
    fill_seg_tables<NB2>((u32*)el32, (u32*)el32 + NB2, hist + (size_t)s * (TILES * NB2), t, tid);
    __syncthreads();

    const u64 ltmask = (1ull << lane) - 1ull;
    u32 dg[8], pk[8];
    volatile u16* vwh = wh;
    #pragma unroll 2
    for (int i = 0; i < 8; ++i) {
        u32 d = (v[i] >> 16) & (NB2 - 1);
        u64 m = matchN<11>(d);
        u32 before = (u32)__popcll(m & ltmask);
        u32 cnt = (u32)__popcll(m);
        bool lead = (lane == __ffsll((unsigned long long)m) - 1);
        dg[i] = d;
        pk[i] = before | (cnt << 8) | (lead ? 0x10000u : 0u);
        if (lead) { u32 p = d * 8 + w; vwh[p] = (u16)(vwh[p] + cnt); }
    }
    __syncthreads();
    block_scan<NB2>((const u32*)el32, (const u32*)el32 + NB2, wh, dl, aux, tid, lane, w);
    __syncthreads();

    for (int i = 0; i < 8; ++i) {
        u32 d = dg[i];
        u32 before = pk[i] & 0xffu;
        u32 base = vwh[d * 8 + w];
        el32[base + before] = v[i];
        if (pk[i] & 0x10000u) vwh[d * 8 + w] = (u16)(base + ((pk[i] >> 8) & 0xffu));
    }
    __syncthreads();

    const float2* cseg = coords + (size_t)s * Pp;
    float2* oseg = out + (size_t)s * Pp;
    for (int i = 0; i < 8; ++i) {
        int pos = i * NTHR + tid;
        u32 e = el32[pos];
        u32 d = (e >> 16) & (NB2 - 1);
        u32 g = (u32)(u16)(pos + dl[d]);
        if (g < Kk) oseg[g] = cseg[e & 0xffffu];
    }
    const float2* eseg = extra + (size_t)s * NR;
    float2* xseg = out + (size_t)s * Pp + Kk;
    #pragma unroll
    for (int i = 0; i < 2; ++i) {
        int p = t * 1024 + i * NTHR + tid;
        xseg[p] = eseg[p];
    }
}

extern "C" void kernel_launch(void* const* d_in, const int* in_sizes, int n_in,
                              void* d_out, int out_size, void* d_ws, size_t ws_size,
                              hipStream_t stream) {
    (void)in_sizes; (void)n_in; (void)out_size; (void)ws_size;
    const float*  logits = (const float*)d_in[0];   // (B,H,W,C) fp32
    const float2* coords = (const float2*)d_in[1];  // (B,P,2)  fp32
    const float2* extra  = (const float2*)d_in[2];  // (B,NR,2) fp32
    float2* out = (float2*)d_out;

    u64* buf0 = (u64*)d_ws;                          // 25.2 MB
    u64* buf1 = buf0 + (size_t)Bb * Pp;              // 25.2 MB (ping-pong)
    float* planes = (float*)buf1;                    // 4 MB; dead before pass-0 scatter writes buf1
    u32* histA = (u32*)d_out;                        // 3.1 MB pass 0/1 hist (d_out scratch; final pass overwrites all of out)
    u32* histB = (u32*)buf1;                         // pass-2 hist (6.3 MB); buf1 dead after pass-1 scatter

    // ch-0 extract (dense float4) -> compact planes
    extract_kernel<<<1024, 256, 0, stream>>>(logits, planes);
    // sample: planes,coords -> keys(buf0,u64) + pass-0 hist (10-bit)
    sample_key_kernel<<<NBLK, NTHR, 0, stream>>>(planes, coords, buf0, histA);
    // pass 0: bits [16,26)  buf0(u64) -> buf1(u64)
    scatter64_kernel<16, false><<<NBLK, NTHR, 0, stream>>>(buf0, buf1, histA);
    // pass 1: bits [26,36)  buf1(u64) -> buf0(u32 compressed: key[36,47)|idx)
    hist64_kernel<<<NBLK, NTHR, 0, stream>>>(buf1, histA, 26);
    scatter64_kernel<26, true><<<NBLK, NTHR, 0, stream>>>(buf1, buf0, histA);
    // pass 2: 11-bit top digit  buf0(u32) -> out (fused gather+emit+extra)
    hist32_kernel<<<NBLK, NTHR, 0, stream>>>((const u32*)buf0, histB);
    scatter32_final_kernel<<<NBLK, NTHR, 0, stream>>>((const u32*)buf0, histB, coords, extra, out);
}

// Round 13
// 254.906 us; speedup vs baseline: 1.1711x; 1.0070x over previous
//
#include <hip/hip_runtime.h>
#include <stdint.h>

#define Bb 64
#define Hh 128
#define Ww 128
#define Cc 21
#define Pp 49152          // NUM_SAMPLED
#define Kk 36864          // NUM_UNCERTAIN
#define NR 12288          // NUM_RANDOM

// Digit split 10/10/11 over key bits [16,47): passes 0,1 use 10-bit digits
// (write runs ~4); pass 2 gets the 11-bit exponent-dominated digit (skewed
// -> long runs -> coalesced writes).
#define NB0 1024          // pass 0/1 bins
#define NB2 2048          // pass 2 bins
#define TILE 4096         // elements per sort tile
#define TILES 12          // Pp / TILE
#define NBLK (Bb * TILES) // 768 blocks
#define NTHR 512          // 8 waves/block (R8: same LDS/tile, 2x waves/CU)

typedef uint32_t u32;
typedef uint64_t u64;
typedef unsigned short u16;

// XCD-affine decode: all TILES blocks of segment s have blk%8 == s%8 ->
// segment's r/w window stays in one XCD's L2. Heuristic only.
#define DECODE_ST const int s = blk & 63; const int t = blk >> 6;

// N-bit ballot digit-match: mask of lanes in this wave holding digit d.
// (Stable: rank derived from lane order, not atomic return order.)
template<int NBITS>
__device__ __forceinline__ u64 matchN(u32 d) {
    u64 m = ~0ull;
    #pragma unroll
    for (int bit = 0; bit < NBITS; ++bit) {
        u64 bl = __ballot((d >> bit) & 1u);
        m &= ((d >> bit) & 1u) ? bl : ~bl;
    }
    return m;
}

// ---------------------------------------------------------------------------
// Kernel 0: vectorized ch-0 extract. Dense float4 reads (R4 lesson: 84B-
// strided scalar reads are latency-bound at 1.8 TB/s; dense float4 ~6 TB/s).
// ---------------------------------------------------------------------------
__global__ __launch_bounds__(256) void extract_kernel(const float* __restrict__ lg,
                                                      float* __restrict__ planes) {
    const u32 gtid = blockIdx.x * 256 + threadIdx.x;   // [0, 262144)
    const float4* l4 = (const float4*)lg;
    #pragma unroll
    for (u32 it = 0; it < 21; ++it) {
        u32 g = it * 262144u + gtid;                   // [0, 5505024)
        float4 v = l4[g];
        u32 base = g * 4u;
        u32 k = (base + 20u) / 21u;                    // first px with ch0 >= base
        u32 pos = k * 21u - base;
        if (pos < 4u) {
            float val = (pos == 0u) ? v.x : (pos == 1u) ? v.y : (pos == 2u) ? v.z : v.w;
            planes[k] = val;
        }
    }
}

// ---------------------------------------------------------------------------
// Kernel 1: bilinear sample (64 KB compact plane staged via float4), key
// build, fused pass-0 (10-bit) hist. (R8 form — the measured optimum.)
// key = fp32 bits of |interp| (order-isomorphic, non-negative); element =
// (key<<16)|idx; LSD stability supplies the idx tie-break (jax.lax.top_k).
// fp contract OFF: bit-exact arithmetic required.
// ---------------------------------------------------------------------------
__global__ __launch_bounds__(512, 4) void sample_key_kernel(const float* __restrict__ planes,
                                                            const float2* __restrict__ coords,
                                                            u64* __restrict__ keys,
                                                            u32* __restrict__ hist) {
#pragma clang fp contract(off)
    __shared__ float pl[Hh * Ww];      // 64 KB
    __shared__ u32 h[NB0];             // 4 KB
    const int tid = threadIdx.x;
    const int blk = blockIdx.x;
    DECODE_ST

    for (int i = tid; i < NB0; i += NTHR) h[i] = 0;
    const float4* p4 = (const float4*)(planes + (size_t)s * (Hh * Ww));
    float4* l4 = (float4*)pl;
    #pragma unroll
    for (int i = 0; i < 8; ++i) l4[i * NTHR + tid] = p4[i * NTHR + tid];
    __syncthreads();

    #pragma unroll 4
    for (int i = 0; i < 8; ++i) {
        int idx = t * TILE + i * NTHR + tid;           // point index within segment
        int gid = s * Pp + idx;
        float2 c = coords[gid];
        float xf = c.x * 127.0f;                       // coords[...,0] -> H axis
        float yf = c.y * 127.0f;                       // coords[...,1] -> W axis
        float x0 = floorf(xf), x1 = ceilf(xf);
        float y0 = floorf(yf), y1 = ceilf(yf);
        float mux = xf - x0;
        float muy = yf - y0;
        int x0i = (int)x0, x1i = (int)x1, y0i = (int)y0, y1i = (int)y1;
        float p1  = pl[x0i * Ww + y0i];
        float p2  = pl[x1i * Ww + y0i];
        float p3  = pl[x0i * Ww + y1i];
        float p4v = pl[x1i * Ww + y1i];
        float p12 = p1 * (1.0f - mux) + p2 * mux;
        float p34 = p3 * (1.0f - mux) + p4v * mux;
        float r   = p12 * (1.0f - muy) + p34 * muy;
        u32 kb = __float_as_uint(r) & 0x7fffffffu;     // |r| bits
        keys[gid] = ((u64)kb << 16) | (u32)idx;
        atomicAdd(&h[kb & (NB0 - 1)], 1u);             // pass-0 digit (uniform)
    }
    __syncthreads();
    const size_t hbase = ((size_t)s * TILES + t) * NB0;
    for (int d = tid; d < NB0; d += NTHR) hist[hbase + d] = h[d];
}

// ---------------------------------------------------------------------------
// hist64: per-wave privatized tables (8 waves x 1024 bins, uniform digit ->
// negligible collisions). Output layout [s][t][d] (tile-major, coalesced).
// ---------------------------------------------------------------------------
__global__ __launch_bounds__(512, 8) void hist64_kernel(const u64* __restrict__ in,
                                                        u32* __restrict__ hist, int shift) {
    __shared__ u32 h[8][NB0];          // 32 KB
    const int tid = threadIdx.x;
    const int w = tid >> 6;
    const int blk = blockIdx.x;
    DECODE_ST
    for (int i = tid; i < 8 * NB0; i += NTHR) ((u32*)h)[i] = 0;
    __syncthreads();
    const u64* src = in + (size_t)s * Pp + t * TILE;
    #pragma unroll 4
    for (int i = 0; i < 8; ++i) {
        u64 v = src[i * NTHR + tid];
        atomicAdd(&h[w][(u32)(v >> shift) & (NB0 - 1)], 1u);
    }
    __syncthreads();
    const size_t hbase = ((size_t)s * TILES + t) * NB0;
    for (int d = tid; d < NB0; d += NTHR) {
        u32 sum = 0;
        #pragma unroll
        for (int k = 0; k < 8; ++k) sum += h[k][d];
        hist[hbase + d] = sum;
    }
}

// ---------------------------------------------------------------------------
// hist32 (pass 2): 512 thr, 8 per-wave tables of packed u16 pairs (carry
// impossible: per-(wave,digit) count <= 512). 32 KB LDS, 32 waves/CU.
// ---------------------------------------------------------------------------
__global__ __launch_bounds__(512, 8) void hist32_kernel(const u32* __restrict__ in,
                                                        u32* __restrict__ hist) {
    __shared__ u32 h[8][NB2 / 2];      // 32 KB: [wave][digit-pair] packed u16
    const int tid = threadIdx.x;
    const int w = tid >> 6;
    const int blk = blockIdx.x;
    DECODE_ST
    for (int i = tid; i < 8 * (NB2 / 2); i += NTHR) ((u32*)h)[i] = 0;
    __syncthreads();
    const u32* src = in + (size_t)s * Pp + t * TILE;
    #pragma unroll 4
    for (int i = 0; i < 8; ++i) {
        u32 v = src[i * NTHR + tid];
        u32 d = (v >> 16) & (NB2 - 1);                 // 11-bit top digit
        atomicAdd(&h[w][d >> 1], 1u << ((d & 1) * 16));
    }
    __syncthreads();
    const size_t hbase = ((size_t)s * TILES + t) * NB2;
    for (int d = tid; d < NB2; d += NTHR) {
        u32 sum = 0;
        #pragma unroll
        for (int k = 0; k < 8; ++k) sum += (h[k][d >> 1] >> ((d & 1) * 16)) & 0xffffu;
        hist[hbase + d] = sum;
    }
}

// ---------------------------------------------------------------------------
// Offset derivation: raw per-tile hist [s][t][d] ->
//   off[s][d][t] = sum_{d'<d} segtot[d'] + sum_{t'<t} cnt[d][t']
// Seg tables staged in scan scratch (head of el, dead until phase B); dual
// block-scan packed in u64 (local count low, segment count high; no carry).
// R13: wh is now u32[NB][4] of packed u16 per-wave counts (atomic phase A);
// scan reads packed halves and rewrites the same memory as u16 bases
// base[d][w] at ((u16*)wh32)[d*8+w] (little-endian: low half = even wave).
// ---------------------------------------------------------------------------
template<int NB>
__device__ __forceinline__ void fill_seg_tables(u32* sc1v, u32* sc2v,
                                                const u32* hb, int t, int tid) {
    for (int d = tid; d < NB; d += NTHR) {
        u32 tot = 0, pre = 0;
        #pragma unroll
        for (int tt = 0; tt < TILES; ++tt) {
            u32 cv = hb[tt * NB + d];       // coalesced, L2-hot
            tot += cv;
            pre += (tt < t) ? cv : 0;
        }
        sc1v[d] = tot;
        sc2v[d] = pre;
    }
}

template<int NB>
__device__ __forceinline__ void block_scan(const u32* sc1v, const u32* sc2v,
                                           u32* wh32, u16* dl, u64* aux,
                                           int tid, int lane, int w) {
    constexpr int DPB = NB / NTHR;          // digits per thread (2 or 4)
    const int d0 = tid * DPB;
    u32 dtot[DPB], gtot[DPB], gpre[DPB];
    u32 t8l = 0, t8g = 0;
    #pragma unroll
    for (int j = 0; j < DPB; ++j) {
        int d = d0 + j;
        u32 cv = 0;
        #pragma unroll
        for (int q = 0; q < 4; ++q) {
            u32 wd = wh32[d * 4 + q];
            cv += (wd & 0xffffu) + (wd >> 16);
        }
        dtot[j] = cv; t8l += cv;
        gtot[j] = sc1v[d]; gpre[j] = sc2v[d]; t8g += gtot[j];
    }
    u64 own = ((u64)t8g << 32) | t8l;
    u64 sc = own;
    for (int o = 1; o < 64; o <<= 1) {
        u64 n = __shfl_up((unsigned long long)sc, o);
        if (lane >= o) sc += n;
    }
    if (lane == 63) aux[w] = sc;
    __syncthreads();
    if (tid == 0) {
        u64 run = 0;
        #pragma unroll
        for (int i = 0; i < 8; ++i) { u64 x = aux[i]; aux[i] = run; run += x; }
    }
    __syncthreads();
    u64 excl = sc - own + aux[w];
    u32 run_l = (u32)excl;                  // local exclusive base
    u32 run_g = (u32)(excl >> 32);          // segment digit-exclusive base
    u16* wh16 = (u16*)wh32;
    #pragma unroll
    for (int j = 0; j < DPB; ++j) {
        int d = d0 + j;
        u32 ls = run_l;
        u32 g = run_g + gpre[j];            // off[s][d][t]
        dl[d] = (u16)(g - ls);              // exact mod 2^16 (Pp < 65536)
        u32 wd[4];
        #pragma unroll
        for (int q = 0; q < 4; ++q) wd[q] = wh32[d * 4 + q];   // read before overwrite
        u32 acc = ls;
        #pragma unroll
        for (int k = 0; k < 8; ++k) {
            u32 ck = (wd[k >> 1] >> ((k & 1) * 16)) & 0xffffu;
            wh16[d * 8 + k] = (u16)acc;     // base[d][wave k]
            acc += ck;
        }
        run_l += dtot[j];
        run_g += gtot[j];
    }
}

// ---------------------------------------------------------------------------
// Scatter (u64 passes 0,1): stable LDS reorder + run-contiguous global write.
// R13 — de-serialized LDS chains:
//  phase A: leaders count via LDS atomicAdd on packed u16 halves (wavepair
//   per u32; carry impossible at <=512/half). The atomic RETURN (old) is the
//   intra-wave digit prefix 'pre'; all 8 atomics issue back-to-back (waits
//   collapse), then deferred __shfl broadcasts pre from each group leader.
//   Same-wave same-address LDS atomics execute in program order -> pre
//   counts exactly the earlier slots -> rank function identical to R12.
//  phase B: position = base[d][w] + pre + before — plain pipelined reads,
//   NO volatile RMW chain at all.
// COMPRESS (pass 1): emit u32 (key[36,47)<<16)|idx — bits [16,36) spent.
// LDS: 32K el + 16K wh32 + 2K dl = 50.3 KB -> 3 blocks/CU (24 waves/CU).
// ---------------------------------------------------------------------------
template<int SHIFT, bool COMPRESS>
__global__ __launch_bounds__(512, 6) void scatter64_kernel(const u64* __restrict__ in,
                                                           void* __restrict__ outbuf,
                                                           const u32* __restrict__ hist) {
    __shared__ u64 el[TILE];           // 32 KB (head = scan scratch pre-B)
    __shared__ u32 wh32[NB0 * 4];      // 16 KB  [digit][wavepair] packed u16
    __shared__ u16 dl[NB0];            // 2 KB
    __shared__ u64 aux[8];
    const int tid = threadIdx.x;
    const int lane = tid & 63;
    const int w = tid >> 6;
    const int blk = blockIdx.x;
    DECODE_ST
    const u64* src = in + (size_t)s * Pp + t * TILE;

    for (int i = tid; i < NB0 * 4; i += NTHR) wh32[i] = 0;
    u64 v[8];
    #pragma unroll
    for (int i = 0; i < 8; ++i) v[i] = src[w * 512 + i * 64 + lane];
    fill_seg_tables<NB0>((u32*)el, (u32*)el + NB0, hist + (size_t)s * (TILES * NB0), t, tid);
    __syncthreads();

    // phase A: match + pipelined atomic counts (returns deferred)
    const u64 ltmask = (1ull << lane) - 1ull;
    const u32 hsh = (w & 1) * 16;
    u32 dg[8], pk[8], old[8];
    #pragma unroll
    for (int i = 0; i < 8; ++i) {
        u32 d = (u32)(v[i] >> SHIFT) & (NB0 - 1);
        u64 m = matchN<10>(d);
        u32 before = (u32)__popcll(m & ltmask);
        u32 cnt = (u32)__popcll(m);
        u32 ldr = (u32)__ffsll((unsigned long long)m) - 1u;
        dg[i] = d;
        pk[i] = before | (cnt << 8) | (ldr << 16);
        old[i] = 0;
        if (lane == (int)ldr)
            old[i] = atomicAdd(&wh32[d * 4 + (w >> 1)], cnt << hsh);
    }
    u32 pre[8];
    #pragma unroll
    for (int i = 0; i < 8; ++i) {
        u32 ex = (old[i] >> hsh) & 0xffffu;
        pre[i] = __shfl(ex, (int)((pk[i] >> 16) & 0xffu));
    }
    __syncthreads();
    block_scan<NB0>((const u32*)el, (const u32*)el + NB0, wh32, dl, aux, tid, lane, w);
    __syncthreads();

    // phase B: rank -> LDS position, no RMW
    const u16* wh16 = (const u16*)wh32;
    #pragma unroll
    for (int i = 0; i < 8; ++i) {
        u32 d = dg[i];
        u32 base = wh16[d * 8 + w];
        el[base + pre[i] + (pk[i] & 0xffu)] = v[i];
    }
    __syncthreads();

    if (!COMPRESS) {
        u64* dst = (u64*)outbuf + (size_t)s * Pp;
        for (int i = 0; i < 8; ++i) {
            int pos = i * NTHR + tid;
            u64 e = el[pos];
            u32 d = (u32)(e >> SHIFT) & (NB0 - 1);
            u32 g = (u32)(u16)(pos + dl[d]);
            dst[g] = e;
        }
    } else {
        u32* dst = (u32*)outbuf + (size_t)s * Pp;
        for (int i = 0; i < 8; ++i) {
            int pos = i * NTHR + tid;
            u64 e = el[pos];
            u32 d = (u32)(e >> SHIFT) & (NB0 - 1);
            u32 g = (u32)(u16)(pos + dl[d]);
            dst[g] = ((u32)(e >> 36) << 16) | (u32)(e & 0xffffu);   // key[36,47) | idx
        }
    }
}

// ---------------------------------------------------------------------------
// Final scatter (u32, 11-bit top digit): same R13 de-serialization. Emits
// out[s][g] = coords[s][idx] for g < K; fused extra_random copy [K, P).
// LDS: 16K el32 + 32K wh32 + 4K dl = 52.3 KB -> 3 blocks/CU.
// ---------------------------------------------------------------------------
__global__ __launch_bounds__(512, 6) void scatter32_final_kernel(const u32* __restrict__ in,
                                                                 const u32* __restrict__ hist,
                                                                 const float2* __restrict__ coords,
                                                                 const float2* __restrict__ extra,
                                                                 float2* __restrict__ out) {
    __shared__ u32 el32[TILE];         // 16 KB (head = scan scratch pre-B)
    __shared__ u32 wh32[NB2 * 4];      // 32 KB  [digit][wavepair] packed u16
    __shared__ u16 dl[NB2];            // 4 KB
    __shared__ u64 aux[8];
    const int tid = threadIdx.x;
    const int lane = tid & 63;
    const int w = tid >> 6;
    const int blk = blockIdx.x;
    DECODE_ST
    const u32* src = in + (size_t)s * Pp + t * TILE;

    for (int i = tid; i < NB2 * 4; i += NTHR) wh32[i] = 0;
    u32 v[8];
    #pragma unroll
    for (int i = 0; i < 8; ++i) v[i] = src[w * 512 + i * 64 + lane];
    fill_seg_tables<NB2>((u32*)el32, (u32*)el32 + NB2, hist + (size_t)s * (TILES * NB2), t, tid);
    __syncthreads();

    const u64 ltmask = (1ull << lane) - 1ull;
    const u32 hsh = (w & 1) * 16;
    u32 dg[8], pk[8], old[8];
    #pragma unroll
    for (int i = 0; i < 8; ++i) {
        u32 d = (v[i] >> 16) & (NB2 - 1);
        u64 m = matchN<11>(d);
        u32 before = (u32)__popcll(m & ltmask);
        u32 cnt = (u32)__popcll(m);
        u32 ldr = (u32)__ffsll((unsigned long long)m) - 1u;
        dg[i] = d;
        pk[i] = before | (cnt << 8) | (ldr << 16);
        old[i] = 0;
        if (lane == (int)ldr)
            old[i] = atomicAdd(&wh32[d * 4 + (w >> 1)], cnt << hsh);
    }
    u32 pre[8];
    #pragma unroll
    for (int i = 0; i < 8; ++i) {
        u32 ex = (old[i] >> hsh) & 0xffffu;
        pre[i] = __shfl(ex, (int)((pk[i] >> 16) & 0xffu));
    }
    __syncthreads();
    block_scan<NB2>((const u32*)el32, (const u32*)el32 + NB2, wh32, dl, aux, tid, lane, w);
    __syncthreads();

    const u16* wh16 = (const u16*)wh32;
    #pragma unroll
    for (int i = 0; i < 8; ++i) {
        u32 d = dg[i];
        u32 base = wh16[d * 8 + w];
        el32[base + pre[i] + (pk[i] & 0xffu)] = v[i];
    }
    __syncthreads();

    const float2* cseg = coords + (size_t)s * Pp;
    float2* oseg = out + (size_t)s * Pp;
    for (int i = 0; i < 8; ++i) {
        int pos = i * NTHR + tid;
        u32 e = el32[pos];
        u32 d = (e >> 16) & (NB2 - 1);
        u32 g = (u32)(u16)(pos + dl[d]);
        if (g < Kk) oseg[g] = cseg[e & 0xffffu];
    }
    const float2* eseg = extra + (size_t)s * NR;
    float2* xseg = out + (size_t)s * Pp + Kk;
    #pragma unroll
    for (int i = 0; i < 2; ++i) {
        int p = t * 1024 + i * NTHR + tid;
        xseg[p] = eseg[p];
    }
}

extern "C" void kernel_launch(void* const* d_in, const int* in_sizes, int n_in,
                              void* d_out, int out_size, void* d_ws, size_t ws_size,
                              hipStream_t stream) {
    (void)in_sizes; (void)n_in; (void)out_size; (void)ws_size;
    const float*  logits = (const float*)d_in[0];   // (B,H,W,C) fp32
    const float2* coords = (const float2*)d_in[1];  // (B,P,2)  fp32
    const float2* extra  = (const float2*)d_in[2];  // (B,NR,2) fp32
    float2* out = (float2*)d_out;

    u64* buf0 = (u64*)d_ws;                          // 25.2 MB
    u64* buf1 = buf0 + (size_t)Bb * Pp;              // 25.2 MB (ping-pong)
    float* planes = (float*)buf1;                    // 4 MB; dead before pass-0 scatter writes buf1
    u32* histA = (u32*)d_out;                        // 3.1 MB pass 0/1 hist (d_out scratch; final pass overwrites all of out)
    u32* histB = (u32*)buf1;                         // pass-2 hist (6.3 MB); buf1 dead after pass-1 scatter

    // ch-0 extract (dense float4) -> compact planes
    extract_kernel<<<1024, 256, 0, stream>>>(logits, planes);
    // sample: planes,coords -> keys(buf0,u64) + pass-0 hist (10-bit)
    sample_key_kernel<<<NBLK, NTHR, 0, stream>>>(planes, coords, buf0, histA);
    // pass 0: bits [16,26)  buf0(u64) -> buf1(u64)
    scatter64_kernel<16, false><<<NBLK, NTHR, 0, stream>>>(buf0, buf1, histA);
    // pass 1: bits [26,36)  buf1(u64) -> buf0(u32 compressed: key[36,47)|idx)
    hist64_kernel<<<NBLK, NTHR, 0, stream>>>(buf1, histA, 26);
    scatter64_kernel<26, true><<<NBLK, NTHR, 0, stream>>>(buf1, buf0, histA);
    // pass 2: 11-bit top digit  buf0(u32) -> out (fused gather+emit+extra)
    hist32_kernel<<<NBLK, NTHR, 0, stream>>>((const u32*)buf0, histB);
    scatter32_final_kernel<<<NBLK, NTHR, 0, stream>>>((const u32*)buf0, histB, coords, extra, out);
}